// Round 1
// baseline (1018.552 us; speedup 1.0000x reference)
//
#include <hip/hip_runtime.h>

// Problem constants (fixed by setup_inputs)
#define BB 8
#define CIN 64
#define COUT 64
#define NN 2048
#define TT 13
#define KTT 3
#define LL 11
#define CL 704                         // COUT*LL
#define HP_SIZE 11534336LL             // B*COUT*N*L
#define ATT_SIZE 33554432LL            // B*N*N

// ---------------------------------------------------------------------------
// Kernel 1: conv0 (+bias) -> h stored as [b][n][c*11+l]; fused f[b,n] reduce.
// Block: 256 thr = 4 waves; each wave owns one n (4 n per block); lane = c.
// ---------------------------------------------------------------------------
__global__ __launch_bounds__(256) void k_conv(
    const float* __restrict__ x, const float* __restrict__ w0,
    const float* __restrict__ b0, const float* __restrict__ w1,
    float* __restrict__ h, float* __restrict__ f) {
  __shared__ float w0s[192 * 65];      // [ci*3+kt][c] padded 65 (bank-conflict-free both sides)
  __shared__ float xs[4 * 64 * 14];    // [nl][ci][t] padded to 14 (float2-aligned)
  const int tid = threadIdx.x;
  const int b = blockIdx.x >> 9;       // 512 blocks per b
  const int n0 = (blockIdx.x & 511) << 2;

  // stage w0 transposed: read coalesced, write stride-65 (conflict-free)
#pragma unroll
  for (int i = 0; i < 48; ++i) {
    int idx = i * 256 + tid;           // 12288 total
    int c = idx / 192, j = idx % 192;
    w0s[j * 65 + c] = w0[idx];
  }
  // stage x slice for 4 n values: 3328 elements
#pragma unroll
  for (int i = 0; i < 13; ++i) {
    int idx = i * 256 + tid;
    int nl = idx / 832, rem = idx % 832;
    int ci = rem / 13, t = rem % 13;
    xs[(nl * 64 + ci) * 14 + t] = x[(((long long)b * 64 + ci) * 2048 + n0 + nl) * 13 + t];
  }
  __syncthreads();

  const int c = tid & 63, nl = tid >> 6;
  float hacc[11];
  const float bias = b0[c];
#pragma unroll
  for (int l = 0; l < 11; ++l) hacc[l] = bias;

  for (int ci = 0; ci < 64; ++ci) {
    const float2* xr2 = (const float2*)&xs[(nl * 64 + ci) * 14];
    float x13[14];
#pragma unroll
    for (int u = 0; u < 7; ++u) { float2 v = xr2[u]; x13[2 * u] = v.x; x13[2 * u + 1] = v.y; }
    const float w0a = w0s[(ci * 3 + 0) * 65 + c];
    const float w0b = w0s[(ci * 3 + 1) * 65 + c];
    const float w0c = w0s[(ci * 3 + 2) * 65 + c];
#pragma unroll
    for (int l = 0; l < 11; ++l)
      hacc[l] = fmaf(x13[l], w0a, fmaf(x13[l + 1], w0b, fmaf(x13[l + 2], w0c, hacc[l])));
  }

  const int n = n0 + nl;
  float* hrow = h + ((long long)b * 2048 + n) * 704 + c * 11;
  float p = 0.f;
#pragma unroll
  for (int l = 0; l < 11; ++l) {
    hrow[l] = hacc[l];
    p = fmaf(hacc[l], w1[c * 11 + l], p);
  }
  // wave (64-lane) reduction over c
#pragma unroll
  for (int off = 32; off; off >>= 1) p += __shfl_xor(p, off, 64);
  if (c == 0) f[b * 2048 + n] = p;
}

// ---------------------------------------------------------------------------
// Kernel 2: per-batch max of f  (lrelu monotonic -> row max = lrelu(f[q]+maxf))
// ---------------------------------------------------------------------------
__global__ __launch_bounds__(256) void k_maxf(const float* __restrict__ f,
                                              float* __restrict__ maxf) {
  const int b = blockIdx.x, tid = threadIdx.x;
  float m = -1e30f;
  for (int i = tid; i < 2048; i += 256) m = fmaxf(m, f[b * 2048 + i]);
#pragma unroll
  for (int off = 32; off; off >>= 1) m = fmaxf(m, __shfl_xor(m, off, 64));
  __shared__ float red[4];
  if ((tid & 63) == 0) red[tid >> 6] = m;
  __syncthreads();
  if (tid == 0) maxf[b] = fmaxf(fmaxf(red[0], red[1]), fmaxf(red[2], red[3]));
}

// ---------------------------------------------------------------------------
// Kernel 3: softmax row sums -> store reciprocal rs[b,q]
// Block: 4 waves, each wave one q row; f row staged in LDS.
// ---------------------------------------------------------------------------
__global__ __launch_bounds__(256) void k_rowsum(const float* __restrict__ f,
                                                const float* __restrict__ maxf,
                                                float* __restrict__ rs) {
  __shared__ float fs[2048];
  const int b = blockIdx.x >> 9;
  const int q0 = (blockIdx.x & 511) << 2;
  const int tid = threadIdx.x;
#pragma unroll
  for (int i = 0; i < 8; ++i) fs[i * 256 + tid] = f[b * 2048 + i * 256 + tid];
  __syncthreads();
  const int lane = tid & 63, wid = tid >> 6;
  const int q = q0 + wid;
  const float fq = fs[q];
  const float mb = maxf[b];
  float t = fq + mb;
  const float m = t >= 0.f ? t : 0.2f * t;   // row max of lrelu
  float sum = 0.f;
  for (int j = lane; j < 2048; j += 64) {
    float v = fq + fs[j];
    v = v >= 0.f ? v : 0.2f * v;
    sum += __expf(v - m);
  }
#pragma unroll
  for (int off = 32; off; off >>= 1) sum += __shfl_xor(sum, off, 64);
  if (lane == 0) rs[b * 2048 + q] = 1.0f / sum;
}

// ---------------------------------------------------------------------------
// Kernel 4: attention (already transposed): att[b,i,j] = exp(lrelu(fi+fj)-m[j])*rs[j]
// ---------------------------------------------------------------------------
__global__ __launch_bounds__(256) void k_att(const float* __restrict__ f,
                                             const float* __restrict__ maxf,
                                             const float* __restrict__ rs,
                                             float* __restrict__ att) {
  const int b = blockIdx.x >> 11;
  const int i = blockIdx.x & 2047;
  const int tid = threadIdx.x;
  const float fi = f[b * 2048 + i];
  const float mb = maxf[b];
  const long long base = ((long long)(b * 2048 + i)) * 2048;
#pragma unroll
  for (int it = 0; it < 8; ++it) {
    int j = it * 256 + tid;
    float fj = f[b * 2048 + j];
    float rsj = rs[b * 2048 + j];
    float v = fi + fj;
    v = v >= 0.f ? v : 0.2f * v;
    float t = fj + mb;
    float mj = t >= 0.f ? t : 0.2f * t;
    att[base + j] = __expf(v - mj) * rsj;
  }
}

// ---------------------------------------------------------------------------
// Kernel 5: h_prime[b,c,q,l] = sum_n att[b,n,q] * h[b,n,c*11+l]
// GEMM per b: Out[(c,l), q], K = n = 2048. Tile: 16 c x 64 q, KT=32.
// Thread (ci, qi): 1 c x 4 q x 11 l = 44 accumulators.
// ---------------------------------------------------------------------------
__global__ __launch_bounds__(256) void k_gemm(const float* __restrict__ h,
                                              const float* __restrict__ att,
                                              float* __restrict__ out) {
  __shared__ float As[32][16][12];   // [kk][c][l] padded to 12
  __shared__ float Bs[32][64];       // [kk][q]
  const int b = blockIdx.z;
  const int ct = blockIdx.y;         // c0 = ct*16
  const int qt = blockIdx.x;         // q0 = qt*64
  const int tid = threadIdx.x;
  const int qi = tid & 15, ci = tid >> 4;
  const float* hb = h + (long long)b * 2048 * 704;
  const float* ab = att + (long long)b * 2048 * 2048;

  float acc[11][4];
#pragma unroll
  for (int l = 0; l < 11; ++l)
#pragma unroll
    for (int qq = 0; qq < 4; ++qq) acc[l][qq] = 0.f;

  for (int k0 = 0; k0 < 2048; k0 += 32) {
    // stage A: 32 rows x 176 contiguous floats
#pragma unroll
    for (int i = 0; i < 22; ++i) {
      int idx = i * 256 + tid;       // 5632 total
      int kk = idx / 176, r = idx % 176;
      As[kk][r / 11][r % 11] = hb[(k0 + kk) * 704 + ct * 176 + r];
    }
    // stage B: 32 x 64
#pragma unroll
    for (int i = 0; i < 8; ++i) {
      int idx = i * 256 + tid;
      Bs[idx >> 6][idx & 63] = ab[(long long)(k0 + (idx >> 6)) * 2048 + qt * 64 + (idx & 63)];
    }
    __syncthreads();
#pragma unroll
    for (int kk = 0; kk < 32; ++kk) {
      float4 a0 = *(const float4*)&As[kk][ci][0];
      float4 a1 = *(const float4*)&As[kk][ci][4];
      float4 a2 = *(const float4*)&As[kk][ci][8];
      float4 bv = *(const float4*)&Bs[kk][qi * 4];
      float av[12] = {a0.x, a0.y, a0.z, a0.w, a1.x, a1.y, a1.z, a1.w,
                      a2.x, a2.y, a2.z, a2.w};
      float bq[4] = {bv.x, bv.y, bv.z, bv.w};
#pragma unroll
      for (int l = 0; l < 11; ++l)
#pragma unroll
        for (int qq = 0; qq < 4; ++qq)
          acc[l][qq] = fmaf(av[l], bq[qq], acc[l][qq]);
    }
    __syncthreads();
  }

  // epilogue: out[b][c][q][l]
  float* ob = out + (long long)b * 64 * 2048 * 11 + (long long)(ct * 16 + ci) * 2048 * 11;
#pragma unroll
  for (int qq = 0; qq < 4; ++qq) {
    int q = qt * 64 + qi * 4 + qq;
    float* o = ob + (long long)q * 11;
#pragma unroll
    for (int l = 0; l < 11; ++l) o[l] = acc[l][qq];
  }
}

// ---------------------------------------------------------------------------
extern "C" void kernel_launch(void* const* d_in, const int* in_sizes, int n_in,
                              void* d_out, int out_size, void* d_ws, size_t ws_size,
                              hipStream_t stream) {
  const float* x  = (const float*)d_in[0];
  const float* w0 = (const float*)d_in[1];
  const float* b0 = (const float*)d_in[2];
  const float* w1 = (const float*)d_in[3];

  float* h    = (float*)d_ws;            // 11,534,336 floats
  float* f    = h + HP_SIZE;             // 16,384
  float* maxf = f + BB * NN;             // 8
  float* rs   = maxf + BB;               // 16,384

  float* hp  = (float*)d_out;            // h_prime
  float* att = hp + HP_SIZE;             // attention (transposed), also GEMM B input

  k_conv<<<dim3(BB * (NN / 4)), dim3(256), 0, stream>>>(x, w0, b0, w1, h, f);
  k_maxf<<<dim3(BB), dim3(256), 0, stream>>>(f, maxf);
  k_rowsum<<<dim3(BB * (NN / 4)), dim3(256), 0, stream>>>(f, maxf, rs);
  k_att<<<dim3(BB * NN), dim3(256), 0, stream>>>(f, maxf, rs, att);
  k_gemm<<<dim3(NN / 64, COUT / 16, BB), dim3(256), 0, stream>>>(h, att, hp);
}

// Round 2
// 318.815 us; speedup vs baseline: 3.1948x; 3.1948x over previous
//
#include <hip/hip_runtime.h>

// Problem constants (fixed by setup_inputs)
#define BB 8
#define CIN 64
#define COUT 64
#define NN 2048
#define TT 13
#define KTT 3
#define LL 11
#define CL 704                         // COUT*LL
#define HP_SIZE 11534336LL             // B*COUT*N*L
#define ATT_SIZE 33554432LL            // B*N*N

typedef __attribute__((ext_vector_type(8))) short bf16x8;
typedef __attribute__((ext_vector_type(4))) float f32x4;

__device__ __forceinline__ unsigned short f2bf(float x) {
  unsigned int u = __float_as_uint(x);
  u += 0x7fffu + ((u >> 16) & 1u);
  return (unsigned short)(u >> 16);
}
__device__ __forceinline__ float bf2f(unsigned short h) {
  return __uint_as_float(((unsigned int)h) << 16);
}

// ---------------------------------------------------------------------------
// Kernel 1: conv0 (+bias) -> h stored as [b][n][c*11+l]; fused f[b,n] reduce.
// ---------------------------------------------------------------------------
__global__ __launch_bounds__(256) void k_conv(
    const float* __restrict__ x, const float* __restrict__ w0,
    const float* __restrict__ b0, const float* __restrict__ w1,
    float* __restrict__ h, float* __restrict__ f) {
  __shared__ float w0s[192 * 65];
  __shared__ float xs[4 * 64 * 14];
  const int tid = threadIdx.x;
  const int b = blockIdx.x >> 9;
  const int n0 = (blockIdx.x & 511) << 2;

#pragma unroll
  for (int i = 0; i < 48; ++i) {
    int idx = i * 256 + tid;
    int c = idx / 192, j = idx % 192;
    w0s[j * 65 + c] = w0[idx];
  }
#pragma unroll
  for (int i = 0; i < 13; ++i) {
    int idx = i * 256 + tid;
    int nl = idx / 832, rem = idx % 832;
    int ci = rem / 13, t = rem % 13;
    xs[(nl * 64 + ci) * 14 + t] = x[(((long long)b * 64 + ci) * 2048 + n0 + nl) * 13 + t];
  }
  __syncthreads();

  const int c = tid & 63, nl = tid >> 6;
  float hacc[11];
  const float bias = b0[c];
#pragma unroll
  for (int l = 0; l < 11; ++l) hacc[l] = bias;

  for (int ci = 0; ci < 64; ++ci) {
    const float2* xr2 = (const float2*)&xs[(nl * 64 + ci) * 14];
    float x13[14];
#pragma unroll
    for (int u = 0; u < 7; ++u) { float2 v = xr2[u]; x13[2 * u] = v.x; x13[2 * u + 1] = v.y; }
    const float w0a = w0s[(ci * 3 + 0) * 65 + c];
    const float w0b = w0s[(ci * 3 + 1) * 65 + c];
    const float w0c = w0s[(ci * 3 + 2) * 65 + c];
#pragma unroll
    for (int l = 0; l < 11; ++l)
      hacc[l] = fmaf(x13[l], w0a, fmaf(x13[l + 1], w0b, fmaf(x13[l + 2], w0c, hacc[l])));
  }

  const int n = n0 + nl;
  float* hrow = h + ((long long)b * 2048 + n) * 704 + c * 11;
  float p = 0.f;
#pragma unroll
  for (int l = 0; l < 11; ++l) {
    hrow[l] = hacc[l];
    p = fmaf(hacc[l], w1[c * 11 + l], p);
  }
#pragma unroll
  for (int off = 32; off; off >>= 1) p += __shfl_xor(p, off, 64);
  if (c == 0) f[b * 2048 + n] = p;
}

// ---------------------------------------------------------------------------
// Kernel 2: per-batch max of f
// ---------------------------------------------------------------------------
__global__ __launch_bounds__(256) void k_maxf(const float* __restrict__ f,
                                              float* __restrict__ maxf) {
  const int b = blockIdx.x, tid = threadIdx.x;
  float m = -1e30f;
  for (int i = tid; i < 2048; i += 256) m = fmaxf(m, f[b * 2048 + i]);
#pragma unroll
  for (int off = 32; off; off >>= 1) m = fmaxf(m, __shfl_xor(m, off, 64));
  __shared__ float red[4];
  if ((tid & 63) == 0) red[tid >> 6] = m;
  __syncthreads();
  if (tid == 0) maxf[b] = fmaxf(fmaxf(red[0], red[1]), fmaxf(red[2], red[3]));
}

// ---------------------------------------------------------------------------
// Kernel 3: softmax row sums -> reciprocal rs[b,q]
// ---------------------------------------------------------------------------
__global__ __launch_bounds__(256) void k_rowsum(const float* __restrict__ f,
                                                const float* __restrict__ maxf,
                                                float* __restrict__ rs) {
  __shared__ float fs[2048];
  const int b = blockIdx.x >> 9;
  const int q0 = (blockIdx.x & 511) << 2;
  const int tid = threadIdx.x;
#pragma unroll
  for (int i = 0; i < 8; ++i) fs[i * 256 + tid] = f[b * 2048 + i * 256 + tid];
  __syncthreads();
  const int lane = tid & 63, wid = tid >> 6;
  const int q = q0 + wid;
  const float fq = fs[q];
  const float mb = maxf[b];
  float t = fq + mb;
  const float m = t >= 0.f ? t : 0.2f * t;
  float sum = 0.f;
  for (int j = lane; j < 2048; j += 64) {
    float v = fq + fs[j];
    v = v >= 0.f ? v : 0.2f * v;
    sum += __expf(v - m);
  }
#pragma unroll
  for (int off = 32; off; off >>= 1) sum += __shfl_xor(sum, off, 64);
  if (lane == 0) rs[b * 2048 + q] = 1.0f / sum;
}

// ---------------------------------------------------------------------------
// Kernel 4: att[b,i,j] = exp(lrelu(fi+fj)-m[j])*rs[j]   (transposed softmax)
// ---------------------------------------------------------------------------
__global__ __launch_bounds__(256) void k_att(const float* __restrict__ f,
                                             const float* __restrict__ maxf,
                                             const float* __restrict__ rs,
                                             float* __restrict__ att) {
  const int b = blockIdx.x >> 11;
  const int i = blockIdx.x & 2047;
  const int tid = threadIdx.x;
  const float fi = f[b * 2048 + i];
  const float mb = maxf[b];
  const long long base = ((long long)(b * 2048 + i)) * 2048;
#pragma unroll
  for (int it = 0; it < 8; ++it) {
    int j = it * 256 + tid;
    float fj = f[b * 2048 + j];
    float rsj = rs[b * 2048 + j];
    float v = fi + fj;
    v = v >= 0.f ? v : 0.2f * v;
    float t = fj + mb;
    float mj = t >= 0.f ? t : 0.2f * t;
    att[base + j] = __expf(v - mj) * rsj;
  }
}

// ---------------------------------------------------------------------------
// Kernel 5: split-bf16 MFMA GEMM.
// C[m=(c,l)][q] = sum_n h[b,n,m] * att[b,n,q], per b.
// BM=176 (11 frags), BN=256, BK=64. 512 thr = 8 waves; wave = full-M x 32q.
// LDS: [kc][row][8k] subtiles, hi+lo planes. 3 MFMAs per (frag,k32) for
// fp32-equivalent precision: Ahi*Bhi + Alo*Bhi + Ahi*Blo.
// ---------------------------------------------------------------------------
#define BM 176
#define BN 256
#define BK 64

__global__ __launch_bounds__(512, 1) void k_gemm(const float* __restrict__ h,
                                                 const float* __restrict__ att,
                                                 float* __restrict__ out) {
  __shared__ short Ah[8 * 176 * 8];   // [kc][m][kk]
  __shared__ short Al[8 * 176 * 8];
  __shared__ short Bh[8 * 256 * 8];   // [kc][q][kk]
  __shared__ short Bl[8 * 256 * 8];

  const int tid = threadIdx.x;
  const int b = blockIdx.z;
  const int ct = blockIdx.y;
  const int qt0 = blockIdx.x * BN;
  const float* hb = h + (long long)b * NN * CL + ct * BM;
  const float* ab = att + (long long)b * NN * NN + qt0;

  const int lane = tid & 63;
  const int w = tid >> 6;        // wave 0..7
  const int qp = lane & 15;      // frag row/col
  const int g = lane >> 4;       // k-group
  const int wq = w * 32;         // wave q-slice

  f32x4 acc[11][2];
#pragma unroll
  for (int mf = 0; mf < 11; ++mf)
#pragma unroll
    for (int nf = 0; nf < 2; ++nf) acc[mf][nf] = (f32x4){0.f, 0.f, 0.f, 0.f};

  const int bq = tid & 255;      // B-stage q
  const int bk0 = tid >> 8;      // 0 or 1

  for (int kt = 0; kt < NN; kt += BK) {
    // ---- stage A: 176 m x 64 k, task=(m, kc), 8 k per task -> 2x b128 write
#pragma unroll
    for (int i = 0; i < 3; ++i) {
      int task = i * 512 + tid;
      if (task < 1408) {
        int kc = task / 176;
        int m = task - kc * 176;
        const float* src = hb + (kt + kc * 8) * CL + m;
        bf16x8 vh, vl;
#pragma unroll
        for (int kk = 0; kk < 8; ++kk) {
          float v = src[kk * CL];
          unsigned short hi = f2bf(v);
          vh[kk] = (short)hi;
          vl[kk] = (short)f2bf(v - bf2f(hi));
        }
        *(bf16x8*)&Ah[(kc * 176 + m) * 8] = vh;
        *(bf16x8*)&Al[(kc * 176 + m) * 8] = vl;
      }
    }
    // ---- stage B: 256 q x 64 k, task=(q, kc)
#pragma unroll
    for (int i = 0; i < 4; ++i) {
      int kc = i * 2 + bk0;
      const float* src = ab + (long long)(kt + kc * 8) * NN + bq;
      bf16x8 vh, vl;
#pragma unroll
      for (int kk = 0; kk < 8; ++kk) {
        float v = src[kk * NN];
        unsigned short hi = f2bf(v);
        vh[kk] = (short)hi;
        vl[kk] = (short)f2bf(v - bf2f(hi));
      }
      *(bf16x8*)&Bh[(kc * 256 + bq) * 8] = vh;
      *(bf16x8*)&Bl[(kc * 256 + bq) * 8] = vl;
    }
    __syncthreads();
    // ---- compute: 2 k32 chunks, 11 m-frags, 2 n-frags, 3 split-MFMAs
#pragma unroll
    for (int kc2 = 0; kc2 < 2; ++kc2) {
      bf16x8 bhf[2], blf[2];
#pragma unroll
      for (int nf = 0; nf < 2; ++nf) {
        int qidx = wq + nf * 16 + qp;
        bhf[nf] = *(const bf16x8*)&Bh[((kc2 * 4 + g) * 256 + qidx) * 8];
        blf[nf] = *(const bf16x8*)&Bl[((kc2 * 4 + g) * 256 + qidx) * 8];
      }
#pragma unroll
      for (int mf = 0; mf < 11; ++mf) {
        int midx = mf * 16 + qp;
        bf16x8 ahf = *(const bf16x8*)&Ah[((kc2 * 4 + g) * 176 + midx) * 8];
        bf16x8 alf = *(const bf16x8*)&Al[((kc2 * 4 + g) * 176 + midx) * 8];
#pragma unroll
        for (int nf = 0; nf < 2; ++nf) {
          acc[mf][nf] = __builtin_amdgcn_mfma_f32_16x16x32_bf16(ahf, bhf[nf], acc[mf][nf], 0, 0, 0);
          acc[mf][nf] = __builtin_amdgcn_mfma_f32_16x16x32_bf16(alf, bhf[nf], acc[mf][nf], 0, 0, 0);
          acc[mf][nf] = __builtin_amdgcn_mfma_f32_16x16x32_bf16(ahf, blf[nf], acc[mf][nf], 0, 0, 0);
        }
      }
    }
    __syncthreads();
  }

  // ---- epilogue: C/D layout col=lane&15 (q), row=(lane>>4)*4+r (m)
  float* ob = out + (long long)b * COUT * NN * LL;
#pragma unroll
  for (int mf = 0; mf < 11; ++mf) {
#pragma unroll
    for (int r = 0; r < 4; ++r) {
      int m = ct * BM + mf * 16 + g * 4 + r;
      int c = m / 11, l = m - c * 11;
      float* orow = ob + (long long)c * NN * LL + l;
#pragma unroll
      for (int nf = 0; nf < 2; ++nf) {
        int q = qt0 + wq + nf * 16 + qp;
        orow[(long long)q * LL] = acc[mf][nf][r];
      }
    }
  }
}

// ---------------------------------------------------------------------------
extern "C" void kernel_launch(void* const* d_in, const int* in_sizes, int n_in,
                              void* d_out, int out_size, void* d_ws, size_t ws_size,
                              hipStream_t stream) {
  const float* x  = (const float*)d_in[0];
  const float* w0 = (const float*)d_in[1];
  const float* b0 = (const float*)d_in[2];
  const float* w1 = (const float*)d_in[3];

  float* h    = (float*)d_ws;            // 11,534,336 floats
  float* f    = h + HP_SIZE;             // 16,384
  float* maxf = f + BB * NN;             // 8
  float* rs   = maxf + BB;               // 16,384

  float* hp  = (float*)d_out;            // h_prime
  float* att = hp + HP_SIZE;             // attention (transposed), GEMM B input

  k_conv<<<dim3(BB * (NN / 4)), dim3(256), 0, stream>>>(x, w0, b0, w1, h, f);
  k_maxf<<<dim3(BB), dim3(256), 0, stream>>>(f, maxf);
  k_rowsum<<<dim3(BB * (NN / 4)), dim3(256), 0, stream>>>(f, maxf, rs);
  k_att<<<dim3(BB * NN), dim3(256), 0, stream>>>(f, maxf, rs, att);
  k_gemm<<<dim3(NN / BN, CL / BM, BB), dim3(512), 0, stream>>>(h, att, hp);
}

// Round 3
// 297.640 us; speedup vs baseline: 3.4221x; 1.0711x over previous
//
#include <hip/hip_runtime.h>

// Problem constants (fixed by setup_inputs)
#define BB 8
#define CIN 64
#define COUT 64
#define NN 2048
#define TT 13
#define KTT 3
#define LL 11
#define CL 704                         // COUT*LL
#define HP_SIZE 11534336LL             // B*COUT*N*L
#define ATT_SIZE 33554432LL            // B*N*N

// GEMM tiling
#define BM 176
#define BN 256
#define BK 32
// Panel geometry (shorts): A per-ks tile = 2pl*4kc*176*8 = 11264; B = 2*4*256*8 = 16384
#define A_TILE 11264
#define B_TILE 16384
#define A_PANEL_TOTAL (23068672LL)     // 4ct*64ks*11264*8b
#define B_PANEL_TOTAL (67108864LL)     // 8qt*64ks*16384*8b
#define WS_SMALL_BYTES 131104ULL       // f+maxf+rs region
#define WS_FULL_BYTES (131104ULL + 2*(23068672ULL + 67108864ULL))

typedef __attribute__((ext_vector_type(8))) short bf16x8;
typedef __attribute__((ext_vector_type(4))) float f32x4;

__device__ __forceinline__ unsigned short f2bf(float x) {
  unsigned int u = __float_as_uint(x);
  u += 0x7fffu + ((u >> 16) & 1u);
  return (unsigned short)(u >> 16);
}
__device__ __forceinline__ float bf2f(unsigned short h) {
  return __uint_as_float(((unsigned int)h) << 16);
}
__device__ __forceinline__ void gl_lds16(const short* g, short* l) {
  __builtin_amdgcn_global_load_lds(
      (const __attribute__((address_space(1))) unsigned int*)g,
      (__attribute__((address_space(3))) unsigned int*)l, 16, 0, 0);
}

// ---------------------------------------------------------------------------
// Kernel 1: conv0 (+bias) -> A panels (bf16 hi/lo, GEMM-ready layout) + f.
// 512 thr = 8 waves; wave w owns n = n0+w, lane = c.
// A panel layout: Apan[b][ct4][ks64][pl2][kc4][176][8] shorts.
// ---------------------------------------------------------------------------
__global__ __launch_bounds__(512) void k_conv(
    const float* __restrict__ x, const float* __restrict__ w0,
    const float* __restrict__ b0, const float* __restrict__ w1,
    short* __restrict__ Apan, float* __restrict__ f) {
  __shared__ float w0s[192 * 65];           // 49920 B
  __shared__ float xs[8 * 64 * 16];         // 32768 B, t-dim padded to 16
  __shared__ __align__(16) short As[2][704 * 8];  // 22528 B  [pl][m][kk]
  const int tid = threadIdx.x;
  const int b = blockIdx.x >> 8;
  const int n0 = (blockIdx.x & 255) << 3;

#pragma unroll
  for (int i = 0; i < 24; ++i) {
    int idx = i * 512 + tid;
    int c = idx / 192, j = idx % 192;
    w0s[j * 65 + c] = w0[idx];
  }
#pragma unroll
  for (int i = 0; i < 13; ++i) {
    int idx = i * 512 + tid;                // 6656 total
    int nl = idx / 832, rem = idx % 832;
    int ci = rem / 13, t = rem % 13;
    xs[(nl * 64 + ci) * 16 + t] = x[(((long long)b * 64 + ci) * 2048 + n0 + nl) * 13 + t];
  }
  __syncthreads();

  const int c = tid & 63, w = tid >> 6;     // w = local n
  float hacc[11];
  const float bias = b0[c];
#pragma unroll
  for (int l = 0; l < 11; ++l) hacc[l] = bias;

  for (int ci = 0; ci < 64; ++ci) {
    const float4* xr = (const float4*)&xs[(w * 64 + ci) * 16];
    float4 va = xr[0], vb = xr[1], vc = xr[2];
    float x13[13] = {va.x, va.y, va.z, va.w, vb.x, vb.y, vb.z, vb.w,
                     vc.x, vc.y, vc.z, vc.w, xs[(w * 64 + ci) * 16 + 12]};
    const float w0a = w0s[(ci * 3 + 0) * 65 + c];
    const float w0b = w0s[(ci * 3 + 1) * 65 + c];
    const float w0c = w0s[(ci * 3 + 2) * 65 + c];
#pragma unroll
    for (int l = 0; l < 11; ++l)
      hacc[l] = fmaf(x13[l], w0a, fmaf(x13[l + 1], w0b, fmaf(x13[l + 2], w0c, hacc[l])));
  }

  // f reduce (lane = c)
  float p = 0.f;
#pragma unroll
  for (int l = 0; l < 11; ++l) p = fmaf(hacc[l], w1[c * 11 + l], p);
#pragma unroll
  for (int off = 32; off; off >>= 1) p += __shfl_xor(p, off, 64);
  if (c == 0) f[b * 2048 + n0 + w] = p;

  // convert + LDS transpose: As[pl][m][kk=w]
#pragma unroll
  for (int l = 0; l < 11; ++l) {
    int m = c * 11 + l;
    unsigned short hi = f2bf(hacc[l]);
    As[0][m * 8 + w] = (short)hi;
    As[1][m * 8 + w] = (short)f2bf(hacc[l] - bf2f(hi));
  }
  __syncthreads();

  // write panels: this block covers ks = n0>>5, kc4 = (n0>>3)&3, full m, kk 0..7
  const int ks = n0 >> 5, kc4 = (n0 >> 3) & 3;
#pragma unroll
  for (int i = 0; i < 3; ++i) {
    int idx = i * 512 + tid;                // 1408 tasks
    if (idx < 1408) {
      int ch = idx / 176, off = idx % 176;
      int ct = ch >> 1, pl = ch & 1;
      long long base = (((((long long)(b * 4 + ct) * 64 + ks) * 2 + pl) * 4 + kc4)) * 1408;
      *(bf16x8*)&Apan[base + off * 8] = *(const bf16x8*)&As[pl][(ct * 176 + off) * 8];
    }
  }
}

// ---------------------------------------------------------------------------
// Kernel 2: per-batch max of f
// ---------------------------------------------------------------------------
__global__ __launch_bounds__(256) void k_maxf(const float* __restrict__ f,
                                              float* __restrict__ maxf) {
  const int b = blockIdx.x, tid = threadIdx.x;
  float m = -1e30f;
  for (int i = tid; i < 2048; i += 256) m = fmaxf(m, f[b * 2048 + i]);
#pragma unroll
  for (int off = 32; off; off >>= 1) m = fmaxf(m, __shfl_xor(m, off, 64));
  __shared__ float red[4];
  if ((tid & 63) == 0) red[tid >> 6] = m;
  __syncthreads();
  if (tid == 0) maxf[b] = fmaxf(fmaxf(red[0], red[1]), fmaxf(red[2], red[3]));
}

// ---------------------------------------------------------------------------
// Kernel 3: softmax row sums -> reciprocal rs[b,q]
// ---------------------------------------------------------------------------
__global__ __launch_bounds__(256) void k_rowsum(const float* __restrict__ f,
                                                const float* __restrict__ maxf,
                                                float* __restrict__ rs) {
  __shared__ float fs[2048];
  const int b = blockIdx.x >> 9;
  const int q0 = (blockIdx.x & 511) << 2;
  const int tid = threadIdx.x;
#pragma unroll
  for (int i = 0; i < 8; ++i) fs[i * 256 + tid] = f[b * 2048 + i * 256 + tid];
  __syncthreads();
  const int lane = tid & 63, wid = tid >> 6;
  const int q = q0 + wid;
  const float fq = fs[q];
  const float mb = maxf[b];
  float t = fq + mb;
  const float m = t >= 0.f ? t : 0.2f * t;
  float sum = 0.f;
  for (int j = lane; j < 2048; j += 64) {
    float v = fq + fs[j];
    v = v >= 0.f ? v : 0.2f * v;
    sum += __expf(v - m);
  }
#pragma unroll
  for (int off = 32; off; off >>= 1) sum += __shfl_xor(sum, off, 64);
  if (lane == 0) rs[b * 2048 + q] = 1.0f / sum;
}

// ---------------------------------------------------------------------------
// Kernel 4a (full-ws path): att fp32 output + B panels (bf16 hi/lo).
// Block = (b, qt, kt64): 256 thr; thread = column j = qt*256+tid.
// B panel layout: Bpan[b][qt8][ks64][pl2][kc4][256][8] shorts.
// ---------------------------------------------------------------------------
__global__ __launch_bounds__(256) void k_bpanel(const float* __restrict__ f,
                                                const float* __restrict__ maxf,
                                                const float* __restrict__ rs,
                                                float* __restrict__ att,
                                                short* __restrict__ Bpan) {
  const int b = blockIdx.x >> 8;
  const int qt = (blockIdx.x >> 5) & 7;
  const int kt = blockIdx.x & 31;
  const int tid = threadIdx.x;
  __shared__ float fi_s[64];
  if (tid < 64) fi_s[tid] = f[b * 2048 + kt * 64 + tid];
  __syncthreads();

  const int j = qt * 256 + tid;
  const float fj = f[b * 2048 + j];
  const float mb = maxf[b];
  float t = fj + mb;
  const float mj = t >= 0.f ? t : 0.2f * t;
  const float rsj = rs[b * 2048 + j];

#pragma unroll
  for (int r = 0; r < 8; ++r) {
    const int ks = kt * 2 + (r >> 2), kc4 = r & 3;
    bf16x8 vh, vl;
#pragma unroll
    for (int u = 0; u < 8; ++u) {
      int i = kt * 64 + r * 8 + u;
      float v = fi_s[r * 8 + u] + fj;
      v = v >= 0.f ? v : 0.2f * v;
      float val = __expf(v - mj) * rsj;
      att[((long long)(b * 2048 + i)) * 2048 + j] = val;
      unsigned short hi = f2bf(val);
      vh[u] = (short)hi;
      vl[u] = (short)f2bf(val - bf2f(hi));
    }
    long long base0 = ((((long long)(b * 8 + qt) * 64 + ks) * 2 + 0) * 4 + kc4) * 2048;
    long long base1 = ((((long long)(b * 8 + qt) * 64 + ks) * 2 + 1) * 4 + kc4) * 2048;
    *(bf16x8*)&Bpan[base0 + tid * 8] = vh;
    *(bf16x8*)&Bpan[base1 + tid * 8] = vl;
  }
}

// ---------------------------------------------------------------------------
// Kernel 4b (fallback path): att fp32 only
// ---------------------------------------------------------------------------
__global__ __launch_bounds__(256) void k_att(const float* __restrict__ f,
                                             const float* __restrict__ maxf,
                                             const float* __restrict__ rs,
                                             float* __restrict__ att) {
  const int b = blockIdx.x >> 11;
  const int i = blockIdx.x & 2047;
  const int tid = threadIdx.x;
  const float fi = f[b * 2048 + i];
  const float mb = maxf[b];
  const long long base = ((long long)(b * 2048 + i)) * 2048;
#pragma unroll
  for (int it = 0; it < 8; ++it) {
    int j = it * 256 + tid;
    float fj = f[b * 2048 + j];
    float rsj = rs[b * 2048 + j];
    float v = fi + fj;
    v = v >= 0.f ? v : 0.2f * v;
    float t = fj + mb;
    float mj = t >= 0.f ? t : 0.2f * t;
    att[base + j] = __expf(v - mj) * rsj;
  }
}

// ---------------------------------------------------------------------------
// Kernel 5: MFMA GEMM, double-buffered BK=32, 2-phase pipeline.
// BPANEL=1: both operands from pre-converted panels via global_load_lds.
// BPANEL=0: A from panels; B reg-loaded from att fp32, converted after compute.
// ---------------------------------------------------------------------------
template <int BPANEL>
__global__ __launch_bounds__(512, 1) void k_gemm(const short* __restrict__ Apan_all,
                                                 const short* __restrict__ Bpan_all,
                                                 const float* __restrict__ att,
                                                 float* __restrict__ out) {
  __shared__ __align__(16) short lds[2][27648];   // [A 11264 | B 16384] shorts
  const int tid = threadIdx.x;
  const int b = blockIdx.z, ct = blockIdx.y, qt = blockIdx.x;
  const int w = tid >> 6, lane = tid & 63, qp = lane & 15, g = lane >> 4;
  const int wq = w * 32;
  const short* Apan = Apan_all + (long long)(b * 4 + ct) * 64 * A_TILE;
  const short* Bpan = Bpan_all + (long long)(b * 8 + qt) * 64 * B_TILE;
  const float* ab = att + (long long)b * NN * NN + qt * 256;
  const int qB = tid & 255, kh = tid >> 8;   // path-B staging coords

  f32x4 acc[11][2];
#pragma unroll
  for (int mf = 0; mf < 11; ++mf)
#pragma unroll
    for (int nf = 0; nf < 2; ++nf) acc[mf][nf] = (f32x4){0.f, 0.f, 0.f, 0.f};

  float brg[16];   // path-B register staging

  auto stageA = [&](int ks, int bsel) {
    const short* a = Apan + (long long)ks * A_TILE;
    short* l = &lds[bsel][0];
#pragma unroll
    for (int i = 0; i < 3; ++i) {
      int ch = i * 8 + w;
      if (ch < 22) gl_lds16(a + ch * 512 + lane * 8, l + ch * 512);
    }
  };
  auto stageB_panel = [&](int ks, int bsel) {
    const short* s = Bpan + (long long)ks * B_TILE;
    short* l = &lds[bsel][11264];
#pragma unroll
    for (int i = 0; i < 4; ++i) {
      int ch = i * 8 + w;
      gl_lds16(s + ch * 512 + lane * 8, l + ch * 512);
    }
  };
  auto loadB_regs = [&](int ks) {
#pragma unroll
    for (int t2 = 0; t2 < 2; ++t2) {
      const float* src = ab + ((long long)(ks * 32 + (kh * 2 + t2) * 8)) * NN + qB;
#pragma unroll
      for (int kk = 0; kk < 8; ++kk) brg[t2 * 8 + kk] = src[(long long)kk * NN];
    }
  };
  auto convB_write = [&](int bsel) {
    short* lB = &lds[bsel][11264];
#pragma unroll
    for (int t2 = 0; t2 < 2; ++t2) {
      int kc4 = kh * 2 + t2;
      bf16x8 vh, vl;
#pragma unroll
      for (int kk = 0; kk < 8; ++kk) {
        float v = brg[t2 * 8 + kk];
        unsigned short hi = f2bf(v);
        vh[kk] = (short)hi;
        vl[kk] = (short)f2bf(v - bf2f(hi));
      }
      *(bf16x8*)&lB[(kc4 * 256 + qB) * 8] = vh;
      *(bf16x8*)&lB[((4 + kc4) * 256 + qB) * 8] = vl;
    }
  };
  auto compute = [&](int bsel) {
    const short* A = &lds[bsel][0];
    const short* Bt = &lds[bsel][11264];
    bf16x8 bh[2], bl[2];
#pragma unroll
    for (int nf = 0; nf < 2; ++nf) {
      int q = wq + nf * 16 + qp;
      bh[nf] = *(const bf16x8*)&Bt[(g * 256 + q) * 8];
      bl[nf] = *(const bf16x8*)&Bt[((4 + g) * 256 + q) * 8];
    }
#pragma unroll
    for (int mf = 0; mf < 11; ++mf) {
      int m = mf * 16 + qp;
      bf16x8 ah = *(const bf16x8*)&A[(g * 176 + m) * 8];
      bf16x8 al = *(const bf16x8*)&A[((4 + g) * 176 + m) * 8];
#pragma unroll
      for (int nf = 0; nf < 2; ++nf) {
        acc[mf][nf] = __builtin_amdgcn_mfma_f32_16x16x32_bf16(ah, bh[nf], acc[mf][nf], 0, 0, 0);
        acc[mf][nf] = __builtin_amdgcn_mfma_f32_16x16x32_bf16(al, bh[nf], acc[mf][nf], 0, 0, 0);
        acc[mf][nf] = __builtin_amdgcn_mfma_f32_16x16x32_bf16(ah, bl[nf], acc[mf][nf], 0, 0, 0);
      }
    }
  };

  // prologue
  stageA(0, 0);
  if (BPANEL) {
    stageB_panel(0, 0);
  } else {
    loadB_regs(0);
    convB_write(0);
  }
  __syncthreads();

  int cur = 0;
  for (int ks = 0; ks < 63; ++ks) {
    stageA(ks + 1, cur ^ 1);
    if (BPANEL) {
      stageB_panel(ks + 1, cur ^ 1);
      compute(cur);
    } else {
      loadB_regs(ks + 1);
      compute(cur);
      convB_write(cur ^ 1);
    }
    __syncthreads();   // drains vmcnt (incl. global_load_lds) + lgkmcnt
    cur ^= 1;
  }
  compute(cur);

  // epilogue: C/D layout col(q)=lane&15, row(m)=(lane>>4)*4+r
  float* ob = out + (long long)b * COUT * NN * LL;
#pragma unroll
  for (int mf = 0; mf < 11; ++mf) {
#pragma unroll
    for (int r = 0; r < 4; ++r) {
      int m = ct * BM + mf * 16 + g * 4 + r;
      int c = m / 11, l = m - c * 11;
      float* orow = ob + (long long)c * NN * LL + l;
#pragma unroll
      for (int nf = 0; nf < 2; ++nf) {
        int q = qt * 256 + wq + nf * 16 + qp;
        orow[(long long)q * LL] = acc[mf][nf][r];
      }
    }
  }
}

// ---------------------------------------------------------------------------
extern "C" void kernel_launch(void* const* d_in, const int* in_sizes, int n_in,
                              void* d_out, int out_size, void* d_ws, size_t ws_size,
                              hipStream_t stream) {
  const float* x  = (const float*)d_in[0];
  const float* w0 = (const float*)d_in[1];
  const float* b0 = (const float*)d_in[2];
  const float* w1 = (const float*)d_in[3];

  float* fbuf = (float*)d_ws;                 // 16384
  float* maxf = fbuf + BB * NN;               // 8
  float* rs   = maxf + BB;                    // 16384
  short* Apan = (short*)((char*)d_ws + WS_SMALL_BYTES);
  short* Bpan = (short*)((char*)d_ws + WS_SMALL_BYTES + 2 * A_PANEL_TOTAL);

  float* hp  = (float*)d_out;
  float* att = hp + HP_SIZE;

  const bool full = ws_size >= WS_FULL_BYTES;

  k_conv<<<dim3(BB * 256), dim3(512), 0, stream>>>(x, w0, b0, w1, Apan, fbuf);
  k_maxf<<<dim3(BB), dim3(256), 0, stream>>>(fbuf, maxf);
  k_rowsum<<<dim3(BB * 512), dim3(256), 0, stream>>>(fbuf, maxf, rs);
  if (full) {
    k_bpanel<<<dim3(BB * 256), dim3(256), 0, stream>>>(fbuf, maxf, rs, att, Bpan);
    k_gemm<1><<<dim3(8, 4, 8), dim3(512), 0, stream>>>(Apan, Bpan, att, hp);
  } else {
    k_att<<<dim3(BB * NN), dim3(256), 0, stream>>>(fbuf, maxf, rs, att);
    k_gemm<0><<<dim3(8, 4, 8), dim3(512), 0, stream>>>(Apan, Bpan, att, hp);
  }
}

// Round 4
// 273.521 us; speedup vs baseline: 3.7239x; 1.0882x over previous
//
#include <hip/hip_runtime.h>

// Problem constants (fixed by setup_inputs)
#define BB 8
#define CIN 64
#define COUT 64
#define NN 2048
#define TT 13
#define KTT 3
#define LL 11
#define CL 704                         // COUT*LL
#define HP_SIZE 11534336LL             // B*COUT*N*L
#define ATT_SIZE 33554432LL            // B*N*N

// GEMM tiling
#define BM 176                         // 11 m-frags of 16
#define BN 128                         // 4 waves x 32 q
#define A_TILE 5632                    // 4kc x 176 x 8 fp16 per k-tile(32)
#define WS_SMALL_BYTES 131104ULL       // f + maxf + rs (fp32)

typedef _Float16 f16;
typedef __attribute__((ext_vector_type(8))) _Float16 f16x8;
typedef __attribute__((ext_vector_type(4))) _Float16 f16x4;
typedef __attribute__((ext_vector_type(4))) float f32x4;

// ---------------------------------------------------------------------------
// Kernel 1: conv0 (+bias) -> fp16 A panels (GEMM-ready layout) + f reduce.
// 512 thr = 8 waves; wave w owns n = n0+w, lane = c.
// A panel layout: Apan[b][ct4][ks64][kc4][176][8] fp16; k = ks*32+kc*8+kk.
// ---------------------------------------------------------------------------
__global__ __launch_bounds__(512) void k_conv(
    const float* __restrict__ x, const float* __restrict__ w0,
    const float* __restrict__ b0, const float* __restrict__ w1,
    f16* __restrict__ Apan, float* __restrict__ f) {
  __shared__ float w0s[192 * 65];               // [ci*3+kt][c] pad 65
  __shared__ float xs[8 * 64 * 16];             // [nl][ci][t] pad 16
  __shared__ __align__(16) f16 As[704 * 8];     // [m][kk=w]
  const int tid = threadIdx.x;
  const int b = blockIdx.x >> 8;
  const int n0 = (blockIdx.x & 255) << 3;

#pragma unroll
  for (int i = 0; i < 24; ++i) {
    int idx = i * 512 + tid;
    int c = idx / 192, j = idx % 192;
    w0s[j * 65 + c] = w0[idx];
  }
#pragma unroll
  for (int i = 0; i < 13; ++i) {
    int idx = i * 512 + tid;                    // 6656 total
    int nl = idx / 832, rem = idx % 832;
    int ci = rem / 13, t = rem % 13;
    xs[(nl * 64 + ci) * 16 + t] = x[(((long long)b * 64 + ci) * 2048 + n0 + nl) * 13 + t];
  }
  __syncthreads();

  const int c = tid & 63, w = tid >> 6;         // w = local n
  float hacc[11];
  const float bias = b0[c];
#pragma unroll
  for (int l = 0; l < 11; ++l) hacc[l] = bias;

  for (int ci = 0; ci < 64; ++ci) {
    const float4* xr = (const float4*)&xs[(w * 64 + ci) * 16];
    float4 va = xr[0], vb = xr[1], vc = xr[2];
    float x13[13] = {va.x, va.y, va.z, va.w, vb.x, vb.y, vb.z, vb.w,
                     vc.x, vc.y, vc.z, vc.w, xs[(w * 64 + ci) * 16 + 12]};
    const float w0a = w0s[(ci * 3 + 0) * 65 + c];
    const float w0b = w0s[(ci * 3 + 1) * 65 + c];
    const float w0c = w0s[(ci * 3 + 2) * 65 + c];
#pragma unroll
    for (int l = 0; l < 11; ++l)
      hacc[l] = fmaf(x13[l], w0a, fmaf(x13[l + 1], w0b, fmaf(x13[l + 2], w0c, hacc[l])));
  }

  // f reduce (lane = c)
  float p = 0.f;
#pragma unroll
  for (int l = 0; l < 11; ++l) p = fmaf(hacc[l], w1[c * 11 + l], p);
#pragma unroll
  for (int off = 32; off; off >>= 1) p += __shfl_xor(p, off, 64);
  if (c == 0) f[b * 2048 + n0 + w] = p;

  // fp16 convert + LDS transpose: As[m][kk=w]
#pragma unroll
  for (int l = 0; l < 11; ++l) As[(c * 11 + l) * 8 + w] = (f16)hacc[l];
  __syncthreads();

  // panel write: this block covers ks=n0>>5, kc4=(n0>>3)&3, all 704 m, kk 0..7
  const int ks = n0 >> 5, kc4 = (n0 >> 3) & 3;
#pragma unroll
  for (int i = 0; i < 2; ++i) {
    int m = i * 512 + tid;
    if (m < 704) {
      int ct = m / 176, mo = m % 176;
      long long base = ((long long)(b * 4 + ct) * 64 + ks) * A_TILE + kc4 * 1408 + mo * 8;
      *(f16x8*)&Apan[base] = *(const f16x8*)&As[m * 8];
    }
  }
}

// ---------------------------------------------------------------------------
// Kernel 2: per-batch max of f
// ---------------------------------------------------------------------------
__global__ __launch_bounds__(256) void k_maxf(const float* __restrict__ f,
                                              float* __restrict__ maxf) {
  const int b = blockIdx.x, tid = threadIdx.x;
  float m = -1e30f;
  for (int i = tid; i < 2048; i += 256) m = fmaxf(m, f[b * 2048 + i]);
#pragma unroll
  for (int off = 32; off; off >>= 1) m = fmaxf(m, __shfl_xor(m, off, 64));
  __shared__ float red[4];
  if ((tid & 63) == 0) red[tid >> 6] = m;
  __syncthreads();
  if (tid == 0) maxf[b] = fmaxf(fmaxf(red[0], red[1]), fmaxf(red[2], red[3]));
}

// ---------------------------------------------------------------------------
// Kernel 3: softmax row sums -> reciprocal rs[b,q]
// ---------------------------------------------------------------------------
__global__ __launch_bounds__(256) void k_rowsum(const float* __restrict__ f,
                                                const float* __restrict__ maxf,
                                                float* __restrict__ rs) {
  __shared__ float fs[2048];
  const int b = blockIdx.x >> 9;
  const int q0 = (blockIdx.x & 511) << 2;
  const int tid = threadIdx.x;
#pragma unroll
  for (int i = 0; i < 8; ++i) fs[i * 256 + tid] = f[b * 2048 + i * 256 + tid];
  __syncthreads();
  const int lane = tid & 63, wid = tid >> 6;
  const int q = q0 + wid;
  const float fq = fs[q];
  const float mb = maxf[b];
  float t = fq + mb;
  const float m = t >= 0.f ? t : 0.2f * t;
  float sum = 0.f;
  for (int j = lane; j < 2048; j += 64) {
    float v = fq + fs[j];
    v = v >= 0.f ? v : 0.2f * v;
    sum += __expf(v - m);
  }
#pragma unroll
  for (int off = 32; off; off >>= 1) sum += __shfl_xor(sum, off, 64);
  if (lane == 0) rs[b * 2048 + q] = 1.0f / sum;
}

// ---------------------------------------------------------------------------
// Kernel 4: att[b,i,j] = exp(lrelu(fi+fj)-m[j])*rs[j]   (transposed softmax)
// ---------------------------------------------------------------------------
__global__ __launch_bounds__(256) void k_att(const float* __restrict__ f,
                                             const float* __restrict__ maxf,
                                             const float* __restrict__ rs,
                                             float* __restrict__ att) {
  const int b = blockIdx.x >> 11;
  const int i = blockIdx.x & 2047;
  const int tid = threadIdx.x;
  const float fi = f[b * 2048 + i];
  const float mb = maxf[b];
  const long long base = ((long long)(b * 2048 + i)) * 2048;
#pragma unroll
  for (int it = 0; it < 8; ++it) {
    int j = it * 256 + tid;
    float fj = f[b * 2048 + j];
    float rsj = rs[b * 2048 + j];
    float v = fi + fj;
    v = v >= 0.f ? v : 0.2f * v;
    float t = fj + mb;
    float mj = t >= 0.f ? t : 0.2f * t;
    att[base + j] = __expf(v - mj) * rsj;
  }
}

// ---------------------------------------------------------------------------
// Kernel 5: fp16 2-term MFMA GEMM: C = A * (Bhi + Blo).
// A = h in single fp16 (panels via global_load_lds); B = att fp32 read
// in-loop, converted to fp16 hi/lo in LDS. BM=176, BN=128, BK=32.
// 256 thr = 4 waves (each full-M x 32q); 2 blocks/CU; double-buffered.
// LDS per buffer (fp16 units): A[4kc][176][8] = 5632 | Bhi 4096 | Blo 4096.
// ---------------------------------------------------------------------------
__global__ __launch_bounds__(256, 2) void k_gemm(const f16* __restrict__ Apan,
                                                 const float* __restrict__ att,
                                                 float* __restrict__ out) {
  __shared__ __align__(16) f16 lds[2][13824];
  const int tid = threadIdx.x;
  const int qt = blockIdx.x, ct = blockIdx.y, b = blockIdx.z;
  const int w = tid >> 6, lane = tid & 63, qp = lane & 15, g = lane >> 4;
  const int wq = w * 32;
  const f16* Ab = Apan + (long long)(b * 4 + ct) * 64 * A_TILE;
  const float* ab = att + (long long)b * NN * NN + qt * 128;
  // B staging coords: thread loads 4 rows (k = kg*4+i) x 4 cols (q4*4..+3)
  const int q4 = tid & 31, kg = tid >> 5, kc = kg >> 1, off4 = (kg & 1) * 4;

  f32x4 acc[11][2];
#pragma unroll
  for (int mf = 0; mf < 11; ++mf)
#pragma unroll
    for (int nf = 0; nf < 2; ++nf) acc[mf][nf] = (f32x4){0.f, 0.f, 0.f, 0.f};

  float4 br[4];

  auto stageA = [&](int ks, int bsel) {
    const f16* a = Ab + (long long)ks * A_TILE;
    f16* l = &lds[bsel][0];
#pragma unroll
    for (int i = 0; i < 3; ++i) {
      int ch = i * 4 + w;
      if (ch < 11)
        __builtin_amdgcn_global_load_lds(
            (const __attribute__((address_space(1))) unsigned int*)(a + ch * 512 + lane * 8),
            (__attribute__((address_space(3))) unsigned int*)(l + ch * 512), 16, 0, 0);
    }
  };
  auto loadB = [&](int ks) {
#pragma unroll
    for (int i = 0; i < 4; ++i)
      br[i] = *((const float4*)(ab + (long long)(ks * 32 + kg * 4 + i) * NN) + q4);
  };
  auto convB = [&](int bsel) {
    f16* l = &lds[bsel][0];
#pragma unroll
    for (int qq = 0; qq < 4; ++qq) {
      f16x4 vh, vl;
#pragma unroll
      for (int i = 0; i < 4; ++i) {
        float v = ((const float*)&br[i])[qq];
        f16 hi = (f16)v;
        vh[i] = hi;
        vl[i] = (f16)(v - (float)hi);
      }
      int q = q4 * 4 + qq;
      *(f16x4*)&l[5632 + (kc * 128 + q) * 8 + off4] = vh;
      *(f16x4*)&l[9728 + (kc * 128 + q) * 8 + off4] = vl;
    }
  };
  auto compute = [&](int bsel) {
    const f16* L = &lds[bsel][0];
    f16x8 bh[2], bl[2];
#pragma unroll
    for (int nf = 0; nf < 2; ++nf) {
      int q = wq + nf * 16 + qp;
      bh[nf] = *(const f16x8*)&L[5632 + (g * 128 + q) * 8];
      bl[nf] = *(const f16x8*)&L[9728 + (g * 128 + q) * 8];
    }
#pragma unroll
    for (int mf = 0; mf < 11; ++mf) {
      f16x8 av = *(const f16x8*)&L[(g * 176 + mf * 16 + qp) * 8];
#pragma unroll
      for (int nf = 0; nf < 2; ++nf) {
        acc[mf][nf] = __builtin_amdgcn_mfma_f32_16x16x32_f16(av, bh[nf], acc[mf][nf], 0, 0, 0);
        acc[mf][nf] = __builtin_amdgcn_mfma_f32_16x16x32_f16(av, bl[nf], acc[mf][nf], 0, 0, 0);
      }
    }
  };

  // prologue
  stageA(0, 0);
  loadB(0);
  convB(0);          // compiler inserts vmcnt wait before br use
  __syncthreads();   // drains gl_lds + ds_writes

  int cur = 0;
  for (int ks = 0; ks < 63; ++ks) {
    stageA(ks + 1, cur ^ 1);   // gl_lds into next buffer (in flight over compute)
    loadB(ks + 1);             // global->reg, in flight over compute
    compute(cur);
    convB(cur ^ 1);            // waits br; writes next buffer (safe post-barrier)
    __syncthreads();
    cur ^= 1;
  }
  compute(cur);

  // epilogue: C/D layout col(q)=lane&15, row(m)=(lane>>4)*4+r
  float* ob = out + (long long)b * COUT * NN * LL;
#pragma unroll
  for (int mf = 0; mf < 11; ++mf) {
#pragma unroll
    for (int r = 0; r < 4; ++r) {
      int m = ct * BM + mf * 16 + g * 4 + r;
      int c = m / 11, l2 = m - c * 11;
      float* orow = ob + (long long)c * NN * LL + l2;
#pragma unroll
      for (int nf = 0; nf < 2; ++nf) {
        int q = qt * BN + wq + nf * 16 + qp;
        orow[(long long)q * LL] = acc[mf][nf][r];
      }
    }
  }
}

// ---------------------------------------------------------------------------
extern "C" void kernel_launch(void* const* d_in, const int* in_sizes, int n_in,
                              void* d_out, int out_size, void* d_ws, size_t ws_size,
                              hipStream_t stream) {
  const float* x  = (const float*)d_in[0];
  const float* w0 = (const float*)d_in[1];
  const float* b0 = (const float*)d_in[2];
  const float* w1 = (const float*)d_in[3];

  float* fbuf = (float*)d_ws;                  // 16384
  float* maxf = fbuf + BB * NN;                // 8
  float* rs   = maxf + BB;                     // 16384
  f16* Apan = (f16*)((char*)d_ws + WS_SMALL_BYTES);   // 23.07 MB

  float* hp  = (float*)d_out;
  float* att = hp + HP_SIZE;

  k_conv<<<dim3(BB * 256), dim3(512), 0, stream>>>(x, w0, b0, w1, Apan, fbuf);
  k_maxf<<<dim3(BB), dim3(256), 0, stream>>>(fbuf, maxf);
  k_rowsum<<<dim3(BB * 512), dim3(256), 0, stream>>>(fbuf, maxf, rs);
  k_att<<<dim3(BB * NN), dim3(256), 0, stream>>>(fbuf, maxf, rs, att);
  k_gemm<<<dim3(NN / BN, CL / BM, BB), dim3(256), 0, stream>>>(Apan, att, hp);
}

// Round 5
// 234.367 us; speedup vs baseline: 4.3460x; 1.1671x over previous
//
#include <hip/hip_runtime.h>

// Problem constants (fixed by setup_inputs)
#define BB 8
#define CIN 64
#define COUT 64
#define NN 2048
#define TT 13
#define KTT 3
#define LL 11
#define CL 704                         // COUT*LL
#define HP_SIZE 11534336LL             // B*COUT*N*L
#define ATT_SIZE 33554432LL            // B*N*N

// GEMM tiling
#define BM 176                         // 11 m-frags of 16
#define BN 128                         // 4 waves x 32 q
#define A_TILE 5632                    // 4kc x 176 x 8 fp16 per k-tile(32)
#define WS_SMALL_BYTES 131104ULL       // f + maxf + rs (fp32)

typedef _Float16 f16;
typedef __attribute__((ext_vector_type(8))) _Float16 f16x8;
typedef __attribute__((ext_vector_type(4))) float f32x4;

// ---------------------------------------------------------------------------
// Kernel 1: conv0 (+bias) -> fp16 A panels (GEMM-ready layout) + f reduce.
// 512 thr = 8 waves; wave w owns n = n0+w, lane = c.
// A panel layout: Apan[b][ct4][ks64][kc4][176][8] fp16; k = ks*32+kc*8+kk.
// ---------------------------------------------------------------------------
__global__ __launch_bounds__(512) void k_conv(
    const float* __restrict__ x, const float* __restrict__ w0,
    const float* __restrict__ b0, const float* __restrict__ w1,
    f16* __restrict__ Apan, float* __restrict__ f) {
  __shared__ float w0s[192 * 65];               // [ci*3+kt][c] pad 65
  __shared__ float xs[8 * 64 * 16];             // [nl][ci][t] pad 16
  __shared__ __align__(16) f16 As[704 * 8];     // [m][kk=w]
  const int tid = threadIdx.x;
  const int b = blockIdx.x >> 8;
  const int n0 = (blockIdx.x & 255) << 3;

#pragma unroll
  for (int i = 0; i < 24; ++i) {
    int idx = i * 512 + tid;
    int c = idx / 192, j = idx % 192;
    w0s[j * 65 + c] = w0[idx];
  }
#pragma unroll
  for (int i = 0; i < 13; ++i) {
    int idx = i * 512 + tid;                    // 6656 total
    int nl = idx / 832, rem = idx % 832;
    int ci = rem / 13, t = rem % 13;
    xs[(nl * 64 + ci) * 16 + t] = x[(((long long)b * 64 + ci) * 2048 + n0 + nl) * 13 + t];
  }
  __syncthreads();

  const int c = tid & 63, w = tid >> 6;         // w = local n
  float hacc[11];
  const float bias = b0[c];
#pragma unroll
  for (int l = 0; l < 11; ++l) hacc[l] = bias;

  for (int ci = 0; ci < 64; ++ci) {
    const float4* xr = (const float4*)&xs[(w * 64 + ci) * 16];
    float4 va = xr[0], vb = xr[1], vc = xr[2];
    float x13[13] = {va.x, va.y, va.z, va.w, vb.x, vb.y, vb.z, vb.w,
                     vc.x, vc.y, vc.z, vc.w, xs[(w * 64 + ci) * 16 + 12]};
    const float w0a = w0s[(ci * 3 + 0) * 65 + c];
    const float w0b = w0s[(ci * 3 + 1) * 65 + c];
    const float w0c = w0s[(ci * 3 + 2) * 65 + c];
#pragma unroll
    for (int l = 0; l < 11; ++l)
      hacc[l] = fmaf(x13[l], w0a, fmaf(x13[l + 1], w0b, fmaf(x13[l + 2], w0c, hacc[l])));
  }

  // f reduce (lane = c)
  float p = 0.f;
#pragma unroll
  for (int l = 0; l < 11; ++l) p = fmaf(hacc[l], w1[c * 11 + l], p);
#pragma unroll
  for (int off = 32; off; off >>= 1) p += __shfl_xor(p, off, 64);
  if (c == 0) f[b * 2048 + n0 + w] = p;

  // fp16 convert + LDS transpose: As[m][kk=w]
#pragma unroll
  for (int l = 0; l < 11; ++l) As[(c * 11 + l) * 8 + w] = (f16)hacc[l];
  __syncthreads();

  // panel write: this block covers ks=n0>>5, kc4=(n0>>3)&3, all 704 m, kk 0..7
  const int ks = n0 >> 5, kc4 = (n0 >> 3) & 3;
#pragma unroll
  for (int i = 0; i < 2; ++i) {
    int m = i * 512 + tid;
    if (m < 704) {
      int ct = m / 176, mo = m % 176;
      long long base = ((long long)(b * 4 + ct) * 64 + ks) * A_TILE + kc4 * 1408 + mo * 8;
      *(f16x8*)&Apan[base] = *(const f16x8*)&As[m * 8];
    }
  }
}

// ---------------------------------------------------------------------------
// Kernel 2: per-batch max of f
// ---------------------------------------------------------------------------
__global__ __launch_bounds__(256) void k_maxf(const float* __restrict__ f,
                                              float* __restrict__ maxf) {
  const int b = blockIdx.x, tid = threadIdx.x;
  float m = -1e30f;
  for (int i = tid; i < 2048; i += 256) m = fmaxf(m, f[b * 2048 + i]);
#pragma unroll
  for (int off = 32; off; off >>= 1) m = fmaxf(m, __shfl_xor(m, off, 64));
  __shared__ float red[4];
  if ((tid & 63) == 0) red[tid >> 6] = m;
  __syncthreads();
  if (tid == 0) maxf[b] = fmaxf(fmaxf(red[0], red[1]), fmaxf(red[2], red[3]));
}

// ---------------------------------------------------------------------------
// Kernel 3: softmax row sums -> reciprocal rs[b,q]
// ---------------------------------------------------------------------------
__global__ __launch_bounds__(256) void k_rowsum(const float* __restrict__ f,
                                                const float* __restrict__ maxf,
                                                float* __restrict__ rs) {
  __shared__ float fs[2048];
  const int b = blockIdx.x >> 9;
  const int q0 = (blockIdx.x & 511) << 2;
  const int tid = threadIdx.x;
#pragma unroll
  for (int i = 0; i < 8; ++i) fs[i * 256 + tid] = f[b * 2048 + i * 256 + tid];
  __syncthreads();
  const int lane = tid & 63, wid = tid >> 6;
  const int q = q0 + wid;
  const float fq = fs[q];
  const float mb = maxf[b];
  float t = fq + mb;
  const float m = t >= 0.f ? t : 0.2f * t;
  float sum = 0.f;
  for (int j = lane; j < 2048; j += 64) {
    float v = fq + fs[j];
    v = v >= 0.f ? v : 0.2f * v;
    sum += __expf(v - m);
  }
#pragma unroll
  for (int off = 32; off; off >>= 1) sum += __shfl_xor(sum, off, 64);
  if (lane == 0) rs[b * 2048 + q] = 1.0f / sum;
}

// ---------------------------------------------------------------------------
// Kernel 4: att[b,i,j] = exp(lrelu(fi+fj)-m[j])*rs[j]   (transposed softmax)
// ---------------------------------------------------------------------------
__global__ __launch_bounds__(256) void k_att(const float* __restrict__ f,
                                             const float* __restrict__ maxf,
                                             const float* __restrict__ rs,
                                             float* __restrict__ att) {
  const int b = blockIdx.x >> 11;
  const int i = blockIdx.x & 2047;
  const int tid = threadIdx.x;
  const float fi = f[b * 2048 + i];
  const float mb = maxf[b];
  const long long base = ((long long)(b * 2048 + i)) * 2048;
#pragma unroll
  for (int it = 0; it < 8; ++it) {
    int j = it * 256 + tid;
    float fj = f[b * 2048 + j];
    float rsj = rs[b * 2048 + j];
    float v = fi + fj;
    v = v >= 0.f ? v : 0.2f * v;
    float t = fj + mb;
    float mj = t >= 0.f ? t : 0.2f * t;
    att[base + j] = __expf(v - mj) * rsj;
  }
}

// ---------------------------------------------------------------------------
// Kernel 5: fp16 MFMA GEMM with B computed IN-KERNEL from f (no att reads).
// C[m=(c,l)][q] = sum_n h[n,m] * B[n][q],  B[n][q] = exp(lrelu(f_n+f_q)-m_q)*rs_q.
// A fp16 panels via global_load_lds; B built per tile: thread owns column
// q (=tid&127) x 16 k (=tid>>7 half), writes two f16x8 (conflict-free).
// BM=176, BN=128, BK=32; 256 thr = 4 waves; 2 blocks/CU; double-buffered.
// Block swizzle: all 16 qt-blocks of one (b,ct) land on one XCD -> A in L2.
// ---------------------------------------------------------------------------
__global__ __launch_bounds__(256, 2) void k_gemm(const f16* __restrict__ Apan,
                                                 const float* __restrict__ f,
                                                 const float* __restrict__ maxf,
                                                 const float* __restrict__ rs,
                                                 float* __restrict__ out) {
  __shared__ __align__(16) f16 Abuf[2][A_TILE];
  __shared__ __align__(16) f16 Bbuf[2][4096];
  __shared__ float fs[2048];

  // swizzled decode: p = (g&7) | (qt<<3) | ((g>>3)<<7), g = ct + 4*b
  const int p = blockIdx.x;
  const int g = (p & 7) | ((p >> 7) << 3);
  const int qt = (p >> 3) & 15;
  const int ct = g & 3, b = g >> 2;

  const int tid = threadIdx.x;
  const int w = tid >> 6, lane = tid & 63, qp = lane & 15, gg = lane >> 4;
  const int wq = w * 32;
  const f16* Ab = Apan + (long long)(b * 4 + ct) * 64 * A_TILE;
  const float* fb = f + b * NN;

  // stage f row (8 KB)
#pragma unroll
  for (int i = 0; i < 2; ++i)
    ((float4*)fs)[i * 256 + tid] = ((const float4*)fb)[i * 256 + tid];

  // per-thread B-column params (q fixed)
  const int qb = tid & 127, kh = tid >> 7;
  const float fq = fb[qt * 128 + qb];
  const float mb = maxf[b];
  const float tq = fq + mb;
  const float mq = tq >= 0.f ? tq : 0.2f * tq;
  const float rq = rs[b * NN + qt * 128 + qb];

  f32x4 acc[11][2];
#pragma unroll
  for (int mf = 0; mf < 11; ++mf)
#pragma unroll
    for (int nf = 0; nf < 2; ++nf) acc[mf][nf] = (f32x4){0.f, 0.f, 0.f, 0.f};

  auto stageA = [&](int ks, int bsel) {
    const f16* a = Ab + (long long)ks * A_TILE;
    f16* l = Abuf[bsel];
#pragma unroll
    for (int i = 0; i < 3; ++i) {
      int ch = i * 4 + w;
      if (ch < 11)
        __builtin_amdgcn_global_load_lds(
            (const __attribute__((address_space(1))) unsigned int*)(a + ch * 512 + lane * 8),
            (__attribute__((address_space(3))) unsigned int*)(l + ch * 512), 16, 0, 0);
    }
  };
  auto buildB = [&](int ks, int bsel) {
    f16* Bs = Bbuf[bsel];
    const float* fk = &fs[ks * 32 + kh * 16];
#pragma unroll
    for (int h8 = 0; h8 < 2; ++h8) {
      float4 fa = *(const float4*)&fk[h8 * 8];
      float4 fc = *(const float4*)&fk[h8 * 8 + 4];
      f16x8 v8;
#pragma unroll
      for (int u = 0; u < 8; ++u) {
        float fi = (u < 4) ? ((const float*)&fa)[u] : ((const float*)&fc)[u - 4];
        float v = fq + fi;
        v = v >= 0.f ? v : 0.2f * v;
        v8[u] = (f16)(__expf(v - mq) * rq);
      }
      *(f16x8*)&Bs[((kh * 2 + h8) * 128 + qb) * 8] = v8;   // lane-contig 16B
    }
  };
  auto compute = [&](int bsel) {
    const f16* A = Abuf[bsel];
    const f16* Bt = Bbuf[bsel];
    f16x8 bh[2];
#pragma unroll
    for (int nf = 0; nf < 2; ++nf)
      bh[nf] = *(const f16x8*)&Bt[(gg * 128 + wq + nf * 16 + qp) * 8];
#pragma unroll
    for (int mf = 0; mf < 11; ++mf) {
      f16x8 av = *(const f16x8*)&A[(gg * 176 + mf * 16 + qp) * 8];
#pragma unroll
      for (int nf = 0; nf < 2; ++nf)
        acc[mf][nf] = __builtin_amdgcn_mfma_f32_16x16x32_f16(av, bh[nf], acc[mf][nf], 0, 0, 0);
    }
  };

  // prologue
  stageA(0, 0);
  __syncthreads();     // fs staged (and A0 drained)
  buildB(0, 0);
  __syncthreads();     // B0 visible

  int cur = 0;
  for (int ks = 0; ks < 63; ++ks) {
    stageA(ks + 1, cur ^ 1);      // async gl_lds into next buffer
    buildB(ks + 1, cur ^ 1);      // VALU+exp, writes next buffer
    compute(cur);
    __syncthreads();
    cur ^= 1;
  }
  compute(cur);

  // epilogue: C/D layout col(q)=lane&15, row(m)=(lane>>4)*4+r
  float* ob = out + (long long)b * COUT * NN * LL;
#pragma unroll
  for (int mf = 0; mf < 11; ++mf) {
#pragma unroll
    for (int r = 0; r < 4; ++r) {
      int m = ct * BM + mf * 16 + gg * 4 + r;
      int c = m / 11, l2 = m - c * 11;
      float* orow = ob + (long long)c * NN * LL + l2;
#pragma unroll
      for (int nf = 0; nf < 2; ++nf) {
        int q = qt * BN + wq + nf * 16 + qp;
        orow[(long long)q * LL] = acc[mf][nf][r];
      }
    }
  }
}

// ---------------------------------------------------------------------------
extern "C" void kernel_launch(void* const* d_in, const int* in_sizes, int n_in,
                              void* d_out, int out_size, void* d_ws, size_t ws_size,
                              hipStream_t stream) {
  const float* x  = (const float*)d_in[0];
  const float* w0 = (const float*)d_in[1];
  const float* b0 = (const float*)d_in[2];
  const float* w1 = (const float*)d_in[3];

  float* fbuf = (float*)d_ws;                  // 16384
  float* maxf = fbuf + BB * NN;                // 8
  float* rs   = maxf + BB;                     // 16384
  f16* Apan = (f16*)((char*)d_ws + WS_SMALL_BYTES);   // 23.07 MB

  float* hp  = (float*)d_out;
  float* att = hp + HP_SIZE;

  k_conv<<<dim3(BB * 256), dim3(512), 0, stream>>>(x, w0, b0, w1, Apan, fbuf);
  k_maxf<<<dim3(BB), dim3(256), 0, stream>>>(fbuf, maxf);
  k_rowsum<<<dim3(BB * 512), dim3(256), 0, stream>>>(fbuf, maxf, rs);
  k_gemm<<<dim3(512), dim3(256), 0, stream>>>(Apan, fbuf, maxf, rs, hp);
  k_att<<<dim3(BB * NN), dim3(256), 0, stream>>>(fbuf, maxf, rs, att);
}

// Round 6
// 193.913 us; speedup vs baseline: 5.2526x; 1.2086x over previous
//
#include <hip/hip_runtime.h>

// Problem constants (fixed by setup_inputs)
#define BB 8
#define CIN 64
#define COUT 64
#define NN 2048
#define TT 13
#define KTT 3
#define LL 11
#define CL 704                         // COUT*LL
#define HP_SIZE 11534336LL             // B*COUT*N*L
#define ATT_SIZE 33554432LL            // B*N*N

// GEMM tiling
#define BM 176                         // 11 m-frags of 16
#define BN 128                         // 4 waves x 32 q
#define A_TILE 5632                    // 4kc x 176 x 8 fp16 per k-tile(32)
#define WS_SMALL_BYTES 131104ULL       // f + maxf + rs (fp32)

typedef _Float16 f16;
typedef __attribute__((ext_vector_type(8))) _Float16 f16x8;
typedef __attribute__((ext_vector_type(2))) _Float16 f16x2;
typedef __attribute__((ext_vector_type(4))) float f32x4;

__device__ __forceinline__ unsigned int pk16(float a, float b) {
  f16 ha = (f16)a, hb = (f16)b;                    // RTN converts
  unsigned short ua = __builtin_bit_cast(unsigned short, ha);
  unsigned short ub = __builtin_bit_cast(unsigned short, hb);
  return (unsigned int)ua | ((unsigned int)ub << 16);
}
__device__ __forceinline__ f16x2 as_h2(unsigned int u) {
  return __builtin_bit_cast(f16x2, u);
}

// ---------------------------------------------------------------------------
// Kernel 1: conv0 via v_dot2_f32_f16 (ci-pairs fp16, fp32 accum).
// Block: 512 thr = 8 waves; wave w owns n = n0+w; lane = c.
// Outputs: fp16 A panels Apan[b][ct4][ks64][kc4][176][8] + f[b,n].
// ---------------------------------------------------------------------------
__global__ __launch_bounds__(512) void k_conv(
    const float* __restrict__ x, const float* __restrict__ w0,
    const float* __restrict__ b0, const float* __restrict__ w1,
    f16* __restrict__ Apan, float* __restrict__ f) {
  __shared__ unsigned int w0pk[96 * 64];       // [cip*3+kt][c] v2f16  24KB
  __shared__ unsigned int xspk[8 * 32 * 16];   // [n][cip][t pad16] v2f16 16KB
  __shared__ f16 As[704 * 10];                 // [m][kk8 + 2pad]  14KB
  const int tid = threadIdx.x;
  const int b = blockIdx.x >> 8;
  const int n0 = (blockIdx.x & 255) << 3;

  // stage w0 packed over ci-pairs: task r=cip*3+kt, c
#pragma unroll
  for (int i = 0; i < 12; ++i) {
    int task = i * 512 + tid;                  // 6144 total
    int c = task & 63, r = task >> 6;
    int kt = r % 3, cip = r / 3;
    float ev = w0[c * 192 + cip * 6 + kt];
    float od = w0[c * 192 + cip * 6 + 3 + kt];
    w0pk[r * 64 + c] = pk16(ev, od);
  }
  // stage x packed: task = ((n*32)+cip)*13 + t
#pragma unroll
  for (int i = 0; i < 7; ++i) {
    int task = i * 512 + tid;                  // 3328 total
    if (task < 3328) {
      int t = task % 13, rest = task / 13;
      int cip = rest & 31, n = rest >> 5;
      long long base = ((long long)(b * 64 + 2 * cip) * 2048 + n0 + n) * 13 + t;
      float ev = x[base];
      float od = x[base + 26624];              // +2048*13 (next ci)
      xspk[(n * 32 + cip) * 16 + t] = pk16(ev, od);
    }
  }
  __syncthreads();

  const int c = tid & 63, w = tid >> 6;        // lane = c, wave = local n
  float acc[11];
  const float bias = b0[c];
#pragma unroll
  for (int l = 0; l < 11; ++l) acc[l] = bias;

  for (int cip = 0; cip < 32; ++cip) {
    const unsigned int* xr = &xspk[(w * 32 + cip) * 16];
    uint4 xa = *(const uint4*)xr;
    uint4 xb = *(const uint4*)(xr + 4);
    uint4 xc = *(const uint4*)(xr + 8);
    unsigned int x13[13] = {xa.x, xa.y, xa.z, xa.w, xb.x, xb.y, xb.z, xb.w,
                            xc.x, xc.y, xc.z, xc.w, xr[12]};
    f16x2 wk0 = as_h2(w0pk[(cip * 3 + 0) * 64 + c]);
    f16x2 wk1 = as_h2(w0pk[(cip * 3 + 1) * 64 + c]);
    f16x2 wk2 = as_h2(w0pk[(cip * 3 + 2) * 64 + c]);
#pragma unroll
    for (int l = 0; l < 11; ++l) {
      acc[l] = __builtin_amdgcn_fdot2(as_h2(x13[l]), wk0, acc[l], false);
      acc[l] = __builtin_amdgcn_fdot2(as_h2(x13[l + 1]), wk1, acc[l], false);
      acc[l] = __builtin_amdgcn_fdot2(as_h2(x13[l + 2]), wk2, acc[l], false);
    }
  }

  // f reduce (lane = c)
  float p = 0.f;
#pragma unroll
  for (int l = 0; l < 11; ++l) p = fmaf(acc[l], w1[c * 11 + l], p);
#pragma unroll
  for (int off = 32; off; off >>= 1) p += __shfl_xor(p, off, 64);
  if (c == 0) f[b * 2048 + n0 + w] = p;

  // fp16 convert + LDS transpose: As[m][kk=w], row pad 10
#pragma unroll
  for (int l = 0; l < 11; ++l) As[(c * 11 + l) * 10 + w] = (f16)acc[l];
  __syncthreads();

  // panel write: ks = n0>>5, kc4 = (n0>>3)&3, kk 0..7
  const int ks = n0 >> 5, kc4 = (n0 >> 3) & 3;
  const unsigned int* As32 = (const unsigned int*)As;
#pragma unroll
  for (int i = 0; i < 2; ++i) {
    int m = i * 512 + tid;
    if (m < 704) {
      uint4 v;
      v.x = As32[m * 5 + 0];
      v.y = As32[m * 5 + 1];
      v.z = As32[m * 5 + 2];
      v.w = As32[m * 5 + 3];
      int ct = m / 176, mo = m - ct * 176;
      long long base = ((long long)(b * 4 + ct) * 64 + ks) * A_TILE + kc4 * 1408 + mo * 8;
      *(uint4*)&Apan[base] = v;
    }
  }
}

// ---------------------------------------------------------------------------
// Kernel 2: per-batch max of f
// ---------------------------------------------------------------------------
__global__ __launch_bounds__(256) void k_maxf(const float* __restrict__ f,
                                              float* __restrict__ maxf) {
  const int b = blockIdx.x, tid = threadIdx.x;
  float m = -1e30f;
  for (int i = tid; i < 2048; i += 256) m = fmaxf(m, f[b * 2048 + i]);
#pragma unroll
  for (int off = 32; off; off >>= 1) m = fmaxf(m, __shfl_xor(m, off, 64));
  __shared__ float red[4];
  if ((tid & 63) == 0) red[tid >> 6] = m;
  __syncthreads();
  if (tid == 0) maxf[b] = fmaxf(fmaxf(red[0], red[1]), fmaxf(red[2], red[3]));
}

// ---------------------------------------------------------------------------
// Kernel 3: softmax row sums -> reciprocal rs[b,q]
// ---------------------------------------------------------------------------
__global__ __launch_bounds__(256) void k_rowsum(const float* __restrict__ f,
                                                const float* __restrict__ maxf,
                                                float* __restrict__ rs) {
  __shared__ float fs[2048];
  const int b = blockIdx.x >> 9;
  const int q0 = (blockIdx.x & 511) << 2;
  const int tid = threadIdx.x;
#pragma unroll
  for (int i = 0; i < 8; ++i) fs[i * 256 + tid] = f[b * 2048 + i * 256 + tid];
  __syncthreads();
  const int lane = tid & 63, wid = tid >> 6;
  const int q = q0 + wid;
  const float fq = fs[q];
  const float mb = maxf[b];
  float t = fq + mb;
  const float m = t >= 0.f ? t : 0.2f * t;
  float sum = 0.f;
  for (int j = lane; j < 2048; j += 64) {
    float v = fq + fs[j];
    v = v >= 0.f ? v : 0.2f * v;
    sum += __expf(v - m);
  }
#pragma unroll
  for (int off = 32; off; off >>= 1) sum += __shfl_xor(sum, off, 64);
  if (lane == 0) rs[b * 2048 + q] = 1.0f / sum;
}

// ---------------------------------------------------------------------------
// Kernel 4: fp16 MFMA GEMM; B (= transposed softmax attention) computed
// in-kernel from f. ct==0 blocks additionally WRITE att fp32 (fuses k_att).
// BM=176, BN=128, BK=32; 256 thr = 4 waves; 2+ blocks/CU; double-buffered.
// Swizzle: 16 qt-blocks of one (b,ct) land on one XCD -> A panel L2-resident.
// ---------------------------------------------------------------------------
__global__ __launch_bounds__(256, 2) void k_gemm(const f16* __restrict__ Apan,
                                                 const float* __restrict__ f,
                                                 const float* __restrict__ maxf,
                                                 const float* __restrict__ rs,
                                                 float* __restrict__ att,
                                                 float* __restrict__ out) {
  __shared__ __align__(16) f16 Abuf[2][A_TILE];
  __shared__ __align__(16) f16 Bbuf[2][4096];
  __shared__ float fs[2048];

  // swizzled decode: p = (g&7) | (qt<<3) | ((g>>3)<<7), g = ct + 4*b
  const int p = blockIdx.x;
  const int g = (p & 7) | ((p >> 7) << 3);
  const int qt = (p >> 3) & 15;
  const int ct = g & 3, b = g >> 2;

  const int tid = threadIdx.x;
  const int w = tid >> 6, lane = tid & 63, qp = lane & 15, gg = lane >> 4;
  const int wq = w * 32;
  const f16* Ab = Apan + (long long)(b * 4 + ct) * 64 * A_TILE;
  const float* fb = f + b * NN;

  // stage f row (8 KB)
#pragma unroll
  for (int i = 0; i < 2; ++i)
    ((float4*)fs)[i * 256 + tid] = ((const float4*)fb)[i * 256 + tid];

  // per-thread B-column params (q fixed)
  const int qb = tid & 127, kh = tid >> 7;
  const float fq = fb[qt * 128 + qb];
  const float mb = maxf[b];
  const float tq = fq + mb;
  const float mq = tq >= 0.f ? tq : 0.2f * tq;
  const float rq = rs[b * NN + qt * 128 + qb];

  f32x4 acc[11][2];
#pragma unroll
  for (int mf = 0; mf < 11; ++mf)
#pragma unroll
    for (int nf = 0; nf < 2; ++nf) acc[mf][nf] = (f32x4){0.f, 0.f, 0.f, 0.f};

  auto stageA = [&](int ks, int bsel) {
    const f16* a = Ab + (long long)ks * A_TILE;
    f16* l = Abuf[bsel];
#pragma unroll
    for (int i = 0; i < 3; ++i) {
      int ch = i * 4 + w;
      if (ch < 11)
        __builtin_amdgcn_global_load_lds(
            (const __attribute__((address_space(1))) unsigned int*)(a + ch * 512 + lane * 8),
            (__attribute__((address_space(3))) unsigned int*)(l + ch * 512), 16, 0, 0);
    }
  };
  auto buildB = [&](int ks, int bsel) {
    f16* Bs = Bbuf[bsel];
    const float* fk = &fs[ks * 32 + kh * 16];
#pragma unroll
    for (int h8 = 0; h8 < 2; ++h8) {
      float4 fa = *(const float4*)&fk[h8 * 8];
      float4 fc = *(const float4*)&fk[h8 * 8 + 4];
      f16x8 v8;
      float vf[8];
#pragma unroll
      for (int u = 0; u < 8; ++u) {
        float fi = (u < 4) ? ((const float*)&fa)[u] : ((const float*)&fc)[u - 4];
        float v = fq + fi;
        v = v >= 0.f ? v : 0.2f * v;
        float val = __expf(v - mq) * rq;
        vf[u] = val;
        v8[u] = (f16)val;
      }
      *(f16x8*)&Bs[((kh * 2 + h8) * 128 + qb) * 8] = v8;   // lane-contig 16B
      if (ct == 0) {
        // fused transposed-attention output (each (n,q) written exactly once)
        long long nb = (long long)(b * 2048 + ks * 32 + kh * 16 + h8 * 8) * 2048;
#pragma unroll
        for (int u = 0; u < 8; ++u)
          att[nb + (long long)u * 2048 + qt * 128 + qb] = vf[u];
      }
    }
  };
  auto compute = [&](int bsel) {
    const f16* A = Abuf[bsel];
    const f16* Bt = Bbuf[bsel];
    f16x8 bh[2];
#pragma unroll
    for (int nf = 0; nf < 2; ++nf)
      bh[nf] = *(const f16x8*)&Bt[(gg * 128 + wq + nf * 16 + qp) * 8];
#pragma unroll
    for (int mf = 0; mf < 11; ++mf) {
      f16x8 av = *(const f16x8*)&A[(gg * 176 + mf * 16 + qp) * 8];
#pragma unroll
      for (int nf = 0; nf < 2; ++nf)
        acc[mf][nf] = __builtin_amdgcn_mfma_f32_16x16x32_f16(av, bh[nf], acc[mf][nf], 0, 0, 0);
    }
  };

  // prologue
  stageA(0, 0);
  __syncthreads();     // fs staged (and A0 drained)
  buildB(0, 0);
  __syncthreads();     // B0 visible

  int cur = 0;
  for (int ks = 0; ks < 63; ++ks) {
    stageA(ks + 1, cur ^ 1);      // async gl_lds into next buffer
    buildB(ks + 1, cur ^ 1);      // VALU+exp (+att store), writes next buffer
    compute(cur);
    __syncthreads();
    cur ^= 1;
  }
  compute(cur);

  // epilogue: C/D layout col(q)=lane&15, row(m)=(lane>>4)*4+r
  float* ob = out + (long long)b * COUT * NN * LL;
#pragma unroll
  for (int mf = 0; mf < 11; ++mf) {
#pragma unroll
    for (int r = 0; r < 4; ++r) {
      int m = ct * BM + mf * 16 + gg * 4 + r;
      int c = m / 11, l2 = m - c * 11;
      float* orow = ob + (long long)c * NN * LL + l2;
#pragma unroll
      for (int nf = 0; nf < 2; ++nf) {
        int q = qt * BN + wq + nf * 16 + qp;
        orow[(long long)q * LL] = acc[mf][nf][r];
      }
    }
  }
}

// ---------------------------------------------------------------------------
extern "C" void kernel_launch(void* const* d_in, const int* in_sizes, int n_in,
                              void* d_out, int out_size, void* d_ws, size_t ws_size,
                              hipStream_t stream) {
  const float* x  = (const float*)d_in[0];
  const float* w0 = (const float*)d_in[1];
  const float* b0 = (const float*)d_in[2];
  const float* w1 = (const float*)d_in[3];

  float* fbuf = (float*)d_ws;                  // 16384
  float* maxf = fbuf + BB * NN;                // 8
  float* rs   = maxf + BB;                     // 16384
  f16* Apan = (f16*)((char*)d_ws + WS_SMALL_BYTES);   // 23.07 MB

  float* hp  = (float*)d_out;
  float* att = hp + HP_SIZE;

  k_conv<<<dim3(BB * 256), dim3(512), 0, stream>>>(x, w0, b0, w1, Apan, fbuf);
  k_maxf<<<dim3(BB), dim3(256), 0, stream>>>(fbuf, maxf);
  k_rowsum<<<dim3(BB * 512), dim3(256), 0, stream>>>(fbuf, maxf, rs);
  k_gemm<<<dim3(512), dim3(256), 0, stream>>>(Apan, fbuf, maxf, rs, att, hp);
}

// Round 7
// 161.252 us; speedup vs baseline: 6.3165x; 1.2026x over previous
//
#include <hip/hip_runtime.h>

// Problem constants (fixed by setup_inputs)
#define BB 8
#define CIN 64
#define COUT 64
#define NN 2048
#define TT 13
#define KTT 3
#define LL 11
#define CL 704                         // COUT*LL
#define HP_SIZE 11534336LL             // B*COUT*N*L

// GEMM tiling
#define BM 176                         // 11 m-frags of 16
#define BN 128                         // 4 waves x 32 q
#define A_TILE 5632                    // 4kc x 176 x 8 fp16 per k-tile(32)

// ws layout (bytes): fbuf 65536 | maxf 32 | tab4 262144 | w0pk 24576 | Apan
#define WS_TAB_OFF 65568ULL
#define WS_W0PK_OFF 327712ULL
#define WS_APAN_OFF 352288ULL

typedef _Float16 f16;
typedef __attribute__((ext_vector_type(8))) _Float16 f16x8;
typedef __attribute__((ext_vector_type(2))) _Float16 f16x2;
typedef __attribute__((ext_vector_type(4))) float f32x4;

__device__ __forceinline__ unsigned int pk16(float a, float b) {
  f16 ha = (f16)a, hb = (f16)b;                    // RTN converts
  unsigned short ua = __builtin_bit_cast(unsigned short, ha);
  unsigned short ub = __builtin_bit_cast(unsigned short, hb);
  return (unsigned int)ua | ((unsigned int)ub << 16);
}
__device__ __forceinline__ f16x2 as_h2(unsigned int u) {
  return __builtin_bit_cast(f16x2, u);
}

// ---------------------------------------------------------------------------
// Kernel 0: pack w0 into ci-pair v2f16 form, once. w0pk_g[(cip*3+kt)*64+c].
// ---------------------------------------------------------------------------
__global__ __launch_bounds__(256) void k_pack(const float* __restrict__ w0,
                                              unsigned int* __restrict__ w0pk_g) {
  int tid = blockIdx.x * 256 + threadIdx.x;        // 6144 total
  int c = tid & 63, r = tid >> 6;                  // r = cip*3+kt, 0..95
  int kt = r % 3, cip = r / 3;
  float ev = w0[c * 192 + cip * 6 + kt];
  float od = w0[c * 192 + cip * 6 + 3 + kt];
  w0pk_g[r * 64 + c] = pk16(ev, od);
}

// ---------------------------------------------------------------------------
// Kernel 1: conv0 via v_dot2_f32_f16 (ci-pairs fp16, fp32 accum).
// Block: 512 thr = 8 waves; wave w owns n = n0+w; lane = c.
// Outputs: fp16 A panels Apan[b][ct4][ks64][kc4][176][8] + f[b,n].
// LDS 55 KB -> 2 blocks/CU.
// ---------------------------------------------------------------------------
__global__ __launch_bounds__(512, 4) void k_conv(
    const float* __restrict__ x, const unsigned int* __restrict__ w0pk_g,
    const float* __restrict__ b0, const float* __restrict__ w1,
    f16* __restrict__ Apan, float* __restrict__ f) {
  __shared__ unsigned int w0pk[96 * 64];       // [cip*3+kt][c]      24 KB
  __shared__ unsigned int xspk[32 * 8 * 16];   // [cip][n][t pad16]  16 KB
  __shared__ f16 As[704 * 10];                 // [m][kk8 + 2pad]    14 KB
  const int tid = threadIdx.x;
  const int b = blockIdx.x >> 8;
  const int n0 = (blockIdx.x & 255) << 3;

  // stage packed w0: coalesced, conflict-free
#pragma unroll
  for (int i = 0; i < 12; ++i) w0pk[i * 512 + tid] = w0pk_g[i * 512 + tid];

  // stage x packed: contiguous 104-dword runs per ci; task = cip*104 + rem
#pragma unroll
  for (int i = 0; i < 7; ++i) {
    int task = i * 512 + tid;                  // 3328 total
    if (task < 3328) {
      int cip = task / 104, rem = task - cip * 104;
      long long base = (long long)(b * 64 + 2 * cip) * 26624 + n0 * 13 + rem;
      float ev = x[base];
      float od = x[base + 26624];              // next ci
      int n = rem / 13, t = rem - n * 13;
      xspk[(cip * 8 + n) * 16 + t] = pk16(ev, od);   // 2-way max (free)
    }
  }
  __syncthreads();

  const int c = tid & 63, w = tid >> 6;        // lane = c, wave = local n
  float acc[11];
  const float bias = b0[c];
#pragma unroll
  for (int l = 0; l < 11; ++l) acc[l] = bias;

  for (int cip = 0; cip < 32; ++cip) {
    const unsigned int* xr = &xspk[(cip * 8 + w) * 16];   // wave-uniform
    uint4 xa = *(const uint4*)xr;
    uint4 xb = *(const uint4*)(xr + 4);
    uint4 xc = *(const uint4*)(xr + 8);
    unsigned int x13[13] = {xa.x, xa.y, xa.z, xa.w, xb.x, xb.y, xb.z, xb.w,
                            xc.x, xc.y, xc.z, xc.w, xr[12]};
    f16x2 wk0 = as_h2(w0pk[(cip * 3 + 0) * 64 + c]);
    f16x2 wk1 = as_h2(w0pk[(cip * 3 + 1) * 64 + c]);
    f16x2 wk2 = as_h2(w0pk[(cip * 3 + 2) * 64 + c]);
#pragma unroll
    for (int l = 0; l < 11; ++l) {
      acc[l] = __builtin_amdgcn_fdot2(as_h2(x13[l]), wk0, acc[l], false);
      acc[l] = __builtin_amdgcn_fdot2(as_h2(x13[l + 1]), wk1, acc[l], false);
      acc[l] = __builtin_amdgcn_fdot2(as_h2(x13[l + 2]), wk2, acc[l], false);
    }
  }

  // f reduce (lane = c)
  float p = 0.f;
#pragma unroll
  for (int l = 0; l < 11; ++l) p = fmaf(acc[l], w1[c * 11 + l], p);
#pragma unroll
  for (int off = 32; off; off >>= 1) p += __shfl_xor(p, off, 64);
  if (c == 0) f[b * 2048 + n0 + w] = p;

  // fp16 convert + LDS transpose: As[m][kk=w], row pad 10 (2-way max)
#pragma unroll
  for (int l = 0; l < 11; ++l) As[(c * 11 + l) * 10 + w] = (f16)acc[l];
  __syncthreads();

  // panel write: ks = n0>>5, kc4 = (n0>>3)&3, kk 0..7
  const int ks = n0 >> 5, kc4 = (n0 >> 3) & 3;
  const unsigned int* As32 = (const unsigned int*)As;
#pragma unroll
  for (int i = 0; i < 2; ++i) {
    int m = i * 512 + tid;
    if (m < 704) {
      uint4 v;
      v.x = As32[m * 5 + 0];
      v.y = As32[m * 5 + 1];
      v.z = As32[m * 5 + 2];
      v.w = As32[m * 5 + 3];
      int ct = m / 176, mo = m - ct * 176;
      long long base = ((long long)(b * 4 + ct) * 64 + ks) * A_TILE + kc4 * 1408 + mo * 8;
      *(uint4*)&Apan[base] = v;
    }
  }
}

// ---------------------------------------------------------------------------
// Kernel 2: per-batch max of f
// ---------------------------------------------------------------------------
__global__ __launch_bounds__(256) void k_maxf(const float* __restrict__ f,
                                              float* __restrict__ maxf) {
  const int b = blockIdx.x, tid = threadIdx.x;
  float m = -1e30f;
  for (int i = tid; i < 2048; i += 256) m = fmaxf(m, f[b * 2048 + i]);
#pragma unroll
  for (int off = 32; off; off >>= 1) m = fmaxf(m, __shfl_xor(m, off, 64));
  __shared__ float red[4];
  if ((tid & 63) == 0) red[tid >> 6] = m;
  __syncthreads();
  if (tid == 0) maxf[b] = fmaxf(fmaxf(red[0], red[1]), fmaxf(red[2], red[3]));
}

// ---------------------------------------------------------------------------
// Kernel 3: softmax row sums + exp-factor table.
// tab4[b*2048+i] = (En, E2n, Rq, Sq):
//   En = exp(f_i - mb)     E2n = exp(0.2 f_i)
//   Rq = rq * (f_i+mb>=0 ? 1 : exp(0.8(f_i+mb)))   Sq = rq * exp(0.2 f_i - m_i)
// so att[n][q] = (fn+fq>=0) ? En*Rq : E2n*Sq  -- exact factorization.
// ---------------------------------------------------------------------------
__global__ __launch_bounds__(256) void k_rowsum(const float* __restrict__ f,
                                                const float* __restrict__ maxf,
                                                float4* __restrict__ tab4) {
  __shared__ float fs[2048];
  const int b = blockIdx.x >> 9;
  const int q0 = (blockIdx.x & 511) << 2;
  const int tid = threadIdx.x;
#pragma unroll
  for (int i = 0; i < 8; ++i) fs[i * 256 + tid] = f[b * 2048 + i * 256 + tid];
  __syncthreads();
  const int lane = tid & 63, wid = tid >> 6;
  const int q = q0 + wid;
  const float fq = fs[q];
  const float mb = maxf[b];
  float t = fq + mb;
  const float m = t >= 0.f ? t : 0.2f * t;     // row max of lrelu
  float sum = 0.f;
  for (int j = lane; j < 2048; j += 64) {
    float v = fq + fs[j];
    v = v >= 0.f ? v : 0.2f * v;
    sum += __expf(v - m);
  }
#pragma unroll
  for (int off = 32; off; off >>= 1) sum += __shfl_xor(sum, off, 64);
  if (lane == 0) {
    float rq = 1.0f / sum;
    float En = __expf(fq - mb);
    float E2 = __expf(0.2f * fq);
    float Rq = t >= 0.f ? rq : rq * __expf(0.8f * t);
    float Sq = rq * __expf(0.2f * fq - m);
    tab4[b * 2048 + q] = make_float4(En, E2, Rq, Sq);
  }
}

// ---------------------------------------------------------------------------
// Kernel 4: fp16 MFMA GEMM; B (transposed softmax attention) built in-kernel
// from the exp-factor table (no transcendentals in the loop). att fp32 output
// is written tile-balanced: block ct stores rows ks in [16ct, 16ct+16).
// BM=176, BN=128, BK=32; 256 thr = 4 waves; 2 blocks/CU; double-buffered.
// Swizzle: 16 qt-blocks of one (b,ct) land on one XCD -> A panel L2-resident.
// ---------------------------------------------------------------------------
__global__ __launch_bounds__(256, 2) void k_gemm(const f16* __restrict__ Apan,
                                                 const float* __restrict__ f,
                                                 const float4* __restrict__ tab4,
                                                 float* __restrict__ att,
                                                 float* __restrict__ out) {
  __shared__ __align__(16) f16 Abuf[2][A_TILE];   // 22528 B
  __shared__ __align__(16) f16 Bbuf[2][4096];     // 16384 B
  __shared__ float fs[2048];                      //  8192 B
  __shared__ __align__(16) float2 Etab[2048];     // 16384 B  (total 63488)

  // swizzled decode: p = (g&7) | (qt<<3) | ((g>>3)<<7), g = ct + 4*b
  const int p = blockIdx.x;
  const int g = (p & 7) | ((p >> 7) << 3);
  const int qt = (p >> 3) & 15;
  const int ct = g & 3, b = g >> 2;

  const int tid = threadIdx.x;
  const int w = tid >> 6, lane = tid & 63, qp = lane & 15, gg = lane >> 4;
  const int wq = w * 32;
  const f16* Ab = Apan + (long long)(b * 4 + ct) * 64 * A_TILE;
  const float* fb = f + b * NN;
  const float4* tb = tab4 + (long long)b * NN;

  // stage f row + (En,E2n) table
#pragma unroll
  for (int i = 0; i < 2; ++i)
    ((float4*)fs)[i * 256 + tid] = ((const float4*)fb)[i * 256 + tid];
#pragma unroll
  for (int i = 0; i < 8; ++i) {
    float4 v = tb[i * 256 + tid];
    Etab[i * 256 + tid] = make_float2(v.x, v.y);
  }

  // per-thread B-column params (q fixed)
  const int qb = tid & 127, kh = tid >> 7;
  const float fq = fb[qt * 128 + qb];
  const float4 myt = tb[qt * 128 + qb];
  const float Rq = myt.z, Sq = myt.w;

  f32x4 acc[11][2];
#pragma unroll
  for (int mf = 0; mf < 11; ++mf)
#pragma unroll
    for (int nf = 0; nf < 2; ++nf) acc[mf][nf] = (f32x4){0.f, 0.f, 0.f, 0.f};

  auto stageA = [&](int ks, int bsel) {
    const f16* a = Ab + (long long)ks * A_TILE;
    f16* l = Abuf[bsel];
#pragma unroll
    for (int i = 0; i < 3; ++i) {
      int ch = i * 4 + w;
      if (ch < 11)
        __builtin_amdgcn_global_load_lds(
            (const __attribute__((address_space(1))) unsigned int*)(a + ch * 512 + lane * 8),
            (__attribute__((address_space(3))) unsigned int*)(l + ch * 512), 16, 0, 0);
    }
  };
  auto buildB = [&](int ks, int bsel) {
    f16* Bs = Bbuf[bsel];
    const int nbase = ks * 32 + kh * 16;
#pragma unroll
    for (int h8 = 0; h8 < 2; ++h8) {
      float4 fA = *(const float4*)&fs[nbase + h8 * 8];
      float4 fB = *(const float4*)&fs[nbase + h8 * 8 + 4];
      const float4* ep = (const float4*)&Etab[nbase + h8 * 8];
      float4 e0 = ep[0], e1 = ep[1], e2 = ep[2], e3 = ep[3];
      float fn[8] = {fA.x, fA.y, fA.z, fA.w, fB.x, fB.y, fB.z, fB.w};
      float Ev[8] = {e0.x, e0.z, e1.x, e1.z, e2.x, e2.z, e3.x, e3.z};
      float E2v[8] = {e0.y, e0.w, e1.y, e1.w, e2.y, e2.w, e3.y, e3.w};
      f16x8 v8;
      float vf[8];
#pragma unroll
      for (int u = 0; u < 8; ++u) {
        bool pos = (fq + fn[u]) >= 0.f;
        float val = (pos ? Ev[u] : E2v[u]) * (pos ? Rq : Sq);
        vf[u] = val;
        v8[u] = (f16)val;
      }
      *(f16x8*)&Bs[((kh * 2 + h8) * 128 + qb) * 8] = v8;   // lane-contig 16B
      if ((ks >> 4) == ct) {
        // balanced fused att output: block ct owns n in [512ct, 512ct+512)
        long long nb = (long long)(b * 2048 + nbase + h8 * 8) * 2048 + qt * 128 + qb;
#pragma unroll
        for (int u = 0; u < 8; ++u) att[nb + (long long)u * 2048] = vf[u];
      }
    }
  };
  auto compute = [&](int bsel) {
    const f16* A = Abuf[bsel];
    const f16* Bt = Bbuf[bsel];
    f16x8 bh[2];
#pragma unroll
    for (int nf = 0; nf < 2; ++nf)
      bh[nf] = *(const f16x8*)&Bt[(gg * 128 + wq + nf * 16 + qp) * 8];
#pragma unroll
    for (int mf = 0; mf < 11; ++mf) {
      f16x8 av = *(const f16x8*)&A[(gg * 176 + mf * 16 + qp) * 8];
#pragma unroll
      for (int nf = 0; nf < 2; ++nf)
        acc[mf][nf] = __builtin_amdgcn_mfma_f32_16x16x32_f16(av, bh[nf], acc[mf][nf], 0, 0, 0);
    }
  };

  // prologue
  stageA(0, 0);
  __syncthreads();     // fs/Etab staged (and A0 drained)
  buildB(0, 0);
  __syncthreads();     // B0 visible

  int cur = 0;
  for (int ks = 0; ks < 63; ++ks) {
    stageA(ks + 1, cur ^ 1);      // async gl_lds into next buffer
    buildB(ks + 1, cur ^ 1);      // VALU only (+att store), writes next buffer
    compute(cur);
    __syncthreads();
    cur ^= 1;
  }
  compute(cur);

  // epilogue: C/D layout col(q)=lane&15, row(m)=(lane>>4)*4+r
  float* ob = out + (long long)b * COUT * NN * LL;
#pragma unroll
  for (int mf = 0; mf < 11; ++mf) {
#pragma unroll
    for (int r = 0; r < 4; ++r) {
      int m = ct * BM + mf * 16 + gg * 4 + r;
      int c = m / 11, l2 = m - c * 11;
      float* orow = ob + (long long)c * NN * LL + l2;
#pragma unroll
      for (int nf = 0; nf < 2; ++nf) {
        int q = qt * BN + wq + nf * 16 + qp;
        orow[(long long)q * LL] = acc[mf][nf][r];
      }
    }
  }
}

// ---------------------------------------------------------------------------
extern "C" void kernel_launch(void* const* d_in, const int* in_sizes, int n_in,
                              void* d_out, int out_size, void* d_ws, size_t ws_size,
                              hipStream_t stream) {
  const float* x  = (const float*)d_in[0];
  const float* w0 = (const float*)d_in[1];
  const float* b0 = (const float*)d_in[2];
  const float* w1 = (const float*)d_in[3];

  float* fbuf = (float*)d_ws;                                   // 16384 f
  float* maxf = fbuf + BB * NN;                                 // 8 f
  float4* tab4 = (float4*)((char*)d_ws + WS_TAB_OFF);           // 16384 float4
  unsigned int* w0pk_g = (unsigned int*)((char*)d_ws + WS_W0PK_OFF);  // 24 KB
  f16* Apan = (f16*)((char*)d_ws + WS_APAN_OFF);                // 23.07 MB

  float* hp  = (float*)d_out;
  float* att = hp + HP_SIZE;

  k_pack<<<dim3(24), dim3(256), 0, stream>>>(w0, w0pk_g);
  k_conv<<<dim3(BB * 256), dim3(512), 0, stream>>>(x, w0pk_g, b0, w1, Apan, fbuf);
  k_maxf<<<dim3(BB), dim3(256), 0, stream>>>(fbuf, maxf);
  k_rowsum<<<dim3(BB * 512), dim3(256), 0, stream>>>(fbuf, maxf, tab4);
  k_gemm<<<dim3(512), dim3(256), 0, stream>>>(Apan, fbuf, tab4, att, hp);
}